// Round 12
// baseline (15453.993 us; speedup 1.0000x reference)
//
#include <hip/hip_runtime.h>

// Problem constants
constexpr int Bsz = 256, Lf = 14, Tt = 500, Hn = 1000;
constexpr int HP = 1024, KP = 1024;     // padded h/k extents
constexpr int NG = 8, GBLK = 32;        // 8 batch-groups of 32 blocks
constexpr int NBLK = 256;

// d_ws layout (identical to r10)
constexpr size_t W_MAT    = (size_t)HP * KP * 2;        // 2 MB bf16 per matrix
constexpr size_t W_SH     = (size_t)HP * KP;            // shorts per matrix
constexpr size_t SB_OFF   = 5 * W_MAT;                  // 10,485,760
// spike planes: [slot:2][layer:3][group:8][b:32][KP] bytes
constexpr size_t SB_BYTES = (size_t)2 * 3 * NG * GBLK * KP;  // 1,572,864
constexpr size_t BAR_OFF  = SB_OFF + SB_BYTES;

typedef __attribute__((ext_vector_type(8)))  short    short8;  // 8 bf16
typedef __attribute__((ext_vector_type(16))) float    f32x16;
typedef __attribute__((ext_vector_type(2)))  unsigned u32x2;
typedef __attribute__((ext_vector_type(4)))  unsigned u32x4v;

// ======================= prep kernel (bf16 weights) =======================
__device__ __forceinline__ unsigned short f2bf(float f) {
  unsigned u = __builtin_bit_cast(unsigned, f);
  unsigned r = (u + 0x7FFFu + ((u >> 16) & 1u)) >> 16;   // RNE
  return (unsigned short)r;
}

__global__ void prep_w(const float* __restrict__ R1, const float* __restrict__ W2,
                       const float* __restrict__ R2, const float* __restrict__ W3,
                       const float* __restrict__ R3, unsigned char* __restrict__ ws) {
  int id  = blockIdx.x * 256 + threadIdx.x;      // 5 * 2^20 threads
  int mat = id >> 20;
  int rem = id & 0xFFFFF;
  int h   = rem >> 10;
  int k   = rem & 1023;
  const float* src = (mat == 0) ? R1 : (mat == 1) ? W2 : (mat == 2) ? R2
                    : (mat == 3) ? W3 : R3;
  float v = (h < Hn && k < Hn) ? src[(size_t)h * Hn + k] : 0.f;
  ((unsigned short*)ws)[(size_t)mat * W_SH + (size_t)h * KP + k] = f2bf(v);
}

// ======================= shared helpers =======================
__device__ __forceinline__ short8 expand8(u32x2 d) {
  // 8 spike bytes (0/1) -> 8 bf16 (0.0/1.0). pair = b0 | b1<<16; *0x3F80.
  unsigned p0 = __umul24(((d[0] & 0xFFu)         | ((d[0] & 0xFF00u) << 8)), 0x3F80u);
  unsigned p1 = __umul24((((d[0] >> 16) & 0xFFu) | ((d[0] >> 24) << 16)),    0x3F80u);
  unsigned p2 = __umul24(((d[1] & 0xFFu)         | ((d[1] & 0xFF00u) << 8)), 0x3F80u);
  unsigned p3 = __umul24((((d[1] >> 16) & 0xFFu) | ((d[1] >> 24) << 16)),    0x3F80u);
  u32x4v u = {p0, p1, p2, p3};
  return __builtin_bit_cast(short8, u);
}

__device__ __forceinline__ f32x16 MF(short8 a, const unsigned short* wp, f32x16 c) {
  short8 b = *(const short8*)wp;
  return __builtin_amdgcn_mfma_f32_32x32x16_bf16(a, b, c, 0, 0, 0);
}

// 16 coherent dwordx2 spike loads, NO wait (burst building block).
__device__ __forceinline__ void spk16_nw(const unsigned char* p, u32x2 d[16]) {
  asm volatile(
    "global_load_dwordx2 %0, %16, off sc0 sc1\n\t"
    "global_load_dwordx2 %1, %16, off offset:16 sc0 sc1\n\t"
    "global_load_dwordx2 %2, %16, off offset:32 sc0 sc1\n\t"
    "global_load_dwordx2 %3, %16, off offset:48 sc0 sc1\n\t"
    "global_load_dwordx2 %4, %16, off offset:64 sc0 sc1\n\t"
    "global_load_dwordx2 %5, %16, off offset:80 sc0 sc1\n\t"
    "global_load_dwordx2 %6, %16, off offset:96 sc0 sc1\n\t"
    "global_load_dwordx2 %7, %16, off offset:112 sc0 sc1\n\t"
    "global_load_dwordx2 %8, %16, off offset:128 sc0 sc1\n\t"
    "global_load_dwordx2 %9, %16, off offset:144 sc0 sc1\n\t"
    "global_load_dwordx2 %10, %16, off offset:160 sc0 sc1\n\t"
    "global_load_dwordx2 %11, %16, off offset:176 sc0 sc1\n\t"
    "global_load_dwordx2 %12, %16, off offset:192 sc0 sc1\n\t"
    "global_load_dwordx2 %13, %16, off offset:208 sc0 sc1\n\t"
    "global_load_dwordx2 %14, %16, off offset:224 sc0 sc1\n\t"
    "global_load_dwordx2 %15, %16, off offset:240 sc0 sc1"
    : "=&v"(d[0]), "=&v"(d[1]), "=&v"(d[2]), "=&v"(d[3]),
      "=&v"(d[4]), "=&v"(d[5]), "=&v"(d[6]), "=&v"(d[7]),
      "=&v"(d[8]), "=&v"(d[9]), "=&v"(d[10]), "=&v"(d[11]),
      "=&v"(d[12]), "=&v"(d[13]), "=&v"(d[14]), "=&v"(d[15])
    : "v"(p) : "memory");
}

// 16 loads WITH wait (r10-proven variant, used by fallback kernel)
__device__ __forceinline__ void spk16(const unsigned char* p, u32x2 d[16]) {
  spk16_nw(p, d);
  asm volatile("s_waitcnt vmcnt(0)" ::: "memory");
}

__device__ __forceinline__ void stream16(f32x16& acc, const unsigned char* sp,
                                         const unsigned short* wp) {
  u32x2 d[16];
  spk16(sp, d);
  __builtin_amdgcn_sched_barrier(0);
#pragma unroll
  for (int kc = 0; kc < 16; ++kc)
    acc = MF(expand8(d[kc]), wp + kc * 16, acc);
}

// ======================= PRIMARY: snn_fast (r10 + 3-plane burst) =======================
__global__ void __launch_bounds__(256, 1)
snn_fast(const float* __restrict__ x, const float* __restrict__ W1,
         unsigned char* __restrict__ ws, float* __restrict__ out)
{
  // [0,9216): reduce (3 waves x 3 tiles x 1024, [j][lane]); [9216,12288): F tiles
  __shared__ float lds[12288];

  const int tid = threadIdx.x;
  const int l   = tid & 63;
  const int w   = tid >> 6;       // wave 0..3 = k-quarter
  const int lr  = l & 31;         // A-row (b) / B-col (h)
  const int lg  = l >> 5;         // k lane-group
  const int blk = blockIdx.x;
  const int g   = blk >> 5;       // batch group
  const int r   = blk & 31;       // rank -> 3 row-tiles
  const int b0  = g * GBLK;

  unsigned char* sb  = ws + SB_OFF;
  unsigned*      bar = (unsigned*)(ws + BAR_OFF);
  unsigned*      cnt = bar + g * 32;
  unsigned*      rel = bar + 512 + g * 32;
  const unsigned short* wb = (const unsigned short*)ws;

  // 3 row-tiles per block (identical mapping to r10)
  int lay[3], hh[3];
  const unsigned short *wA[3], *wB[3];
#pragma unroll
  for (int i = 0; i < 3; ++i) {
    const int rt = r * 3 + i;
    lay[i] = rt >> 5;
    hh[i]  = (rt & 31) * 32;
    const size_t wl = (size_t)(hh[i] + lr) * KP + w * 256 + lg * 8;
    if (lay[i] == 0)      { wA[i] = wb + 0 * W_SH + wl; wB[i] = wb + 0 * W_SH + wl; }
    else if (lay[i] == 1) { wA[i] = wb + 1 * W_SH + wl; wB[i] = wb + 2 * W_SH + wl; }
    else                  { wA[i] = wb + 3 * W_SH + wl; wB[i] = wb + 4 * W_SH + wl; }
  }

  f32x16 v[3];
#pragma unroll
  for (int i = 0; i < 3; ++i)
#pragma unroll
    for (int j = 0; j < 16; ++j) v[i][j] = 0.f;

#pragma unroll 1
  for (int p = 0; p < Tt + 2; ++p) {
    const int srd = (p + 1) & 1;
    const int swr = p & 1;

    // ---- F = x@W1^T for layer-0 tiles (x-only; hoisted ABOVE the gate) ----
#pragma unroll
    for (int i = 0; i < 3; ++i) {
      if (lay[i] != 0) continue;            // uniform per block
      const int fh = tid & 31;
      const int fb = tid >> 5;
      float F0 = 0.f, F1 = 0.f, F2 = 0.f, F3 = 0.f;
      if (p < Tt) {
        const int hrow = hh[i] + fh;
        const float* xq0 = x + (size_t)(b0 + fb)      * (Lf * Tt) + p;
        const float* xq1 = x + (size_t)(b0 + fb + 8)  * (Lf * Tt) + p;
        const float* xq2 = x + (size_t)(b0 + fb + 16) * (Lf * Tt) + p;
        const float* xq3 = x + (size_t)(b0 + fb + 24) * (Lf * Tt) + p;
        const float* w1p = W1 + (size_t)hrow * Lf;
#pragma unroll
        for (int t = 0; t < Lf; ++t) {
          const float wv = (hrow < Hn) ? w1p[t] : 0.f;
          F0 = fmaf(xq0[(size_t)t * Tt], wv, F0);
          F1 = fmaf(xq1[(size_t)t * Tt], wv, F1);
          F2 = fmaf(xq2[(size_t)t * Tt], wv, F2);
          F3 = fmaf(xq3[(size_t)t * Tt], wv, F3);
        }
      }
      float* Fp = &lds[9216 + i * 1024 + fb * 32 + fh];
      Fp[0]       = F0;
      Fp[8 * 32]  = F1;
      Fp[16 * 32] = F2;
      Fp[24 * 32] = F3;
    }

    // ---- gate: group's previous phase fully complete ----
    if (tid == 0) {
      while (__hip_atomic_load(rel, __ATOMIC_RELAXED,
                               __HIP_MEMORY_SCOPE_AGENT) < (unsigned)p)
        __builtin_amdgcn_s_sleep(1);
    }
    __syncthreads();

    // ---- spike loads: 3 planes, ONE round trip ----
    const size_t lanes = (size_t)lr * KP + w * 256 + lg * 8;
    u32x2 d0[16], d1[16], d2[16];
    spk16_nw(sb + ((((size_t)srd * 3 + 0) * NG + g) << 15) + lanes, d0);
    spk16_nw(sb + ((((size_t)srd * 3 + 1) * NG + g) << 15) + lanes, d1);
    spk16_nw(sb + ((((size_t)srd * 3 + 2) * NG + g) << 15) + lanes, d2);
    asm volatile("s_waitcnt vmcnt(0)" ::: "memory");
    __builtin_amdgcn_sched_barrier(0);

    // ---- MFMA: per-tile consumption from the preloaded planes ----
    f32x16 acc[3];
#pragma unroll
    for (int i = 0; i < 3; ++i) {
#pragma unroll
      for (int j = 0; j < 16; ++j) acc[i][j] = 0.f;
      if (lay[i] == 0) {
#pragma unroll
        for (int kc = 0; kc < 16; ++kc)
          acc[i] = MF(expand8(d0[kc]), wA[i] + kc * 16, acc[i]);
      } else if (lay[i] == 1) {
#pragma unroll
        for (int kc = 0; kc < 16; ++kc) {
          acc[i] = MF(expand8(d0[kc]), wA[i] + kc * 16, acc[i]);
          acc[i] = MF(expand8(d1[kc]), wB[i] + kc * 16, acc[i]);
        }
      } else {
#pragma unroll
        for (int kc = 0; kc < 16; ++kc) {
          acc[i] = MF(expand8(d1[kc]), wA[i] + kc * 16, acc[i]);
          acc[i] = MF(expand8(d2[kc]), wB[i] + kc * 16, acc[i]);
        }
      }
    }

    // ---- cross-wave reduce ([j][lane] layout, conflict-free) ----
    if (w != 0) {
      float* dp = &lds[(w - 1) * 3 * 1024 + l];
#pragma unroll
      for (int i = 0; i < 3; ++i)
#pragma unroll
        for (int j = 0; j < 16; ++j) dp[i * 1024 + j * 64] = acc[i][j];
    }
    __syncthreads();

    if (w == 0) {
#pragma unroll
      for (int i = 0; i < 3; ++i) {
        unsigned char* o =
            sb + ((((size_t)swr * 3 + lay[i]) * NG + g) << 15) + hh[i] + lr;
#pragma unroll
        for (int j = 0; j < 16; ++j) {
          const int row = (j & 3) + 8 * (j >> 2) + 4 * lg;   // batch row
          float a = acc[i][j];
#pragma unroll
          for (int ww = 0; ww < 3; ++ww)
            a += lds[(ww * 3 + i) * 1024 + j * 64 + l];
          const float F = (lay[i] == 0) ? lds[9216 + i * 1024 + row * 32 + lr] : 0.f;
          const float vn = 0.5f * (v[i][j] + a + F);
          const unsigned c = (vn >= 1.0f) ? 1u : 0u;
          v[i][j] = c ? 0.f : vn;
          asm volatile("global_store_byte %0, %1, off sc0 sc1"
                       :: "v"(o + (size_t)row * KP), "v"(c) : "memory");
        }
      }
    }

    // ---- arrive (release published by last block; no polling here) ----
    asm volatile("s_waitcnt vmcnt(0)" ::: "memory");   // spike stores visible
    __syncthreads();
    if (tid == 0) {
      unsigned old = __hip_atomic_fetch_add(cnt, 1u, __ATOMIC_RELAXED,
                                            __HIP_MEMORY_SCOPE_AGENT);
      if (old == (unsigned)(p + 1) * GBLK - 1u)
        __hip_atomic_store(rel, (unsigned)(p + 1), __ATOMIC_RELAXED,
                           __HIP_MEMORY_SCOPE_AGENT);
    }
    __syncthreads();
  }

  // ---- output: exp(final v3) from layer-2 tiles ----
  if (w == 0) {
#pragma unroll
    for (int i = 0; i < 3; ++i) {
      if (lay[i] != 2) continue;
      const int h = hh[i] + lr;
      if (h < Hn) {
#pragma unroll
        for (int j = 0; j < 16; ++j) {
          const int row = (j & 3) + 8 * (j >> 2) + 4 * lg;
          out[(size_t)(b0 + row) * Hn + h] = expf(v[i][j]);
        }
      }
    }
  }
}

// ======================= FALLBACK: snn_base (r10 verbatim) =======================
__global__ void __launch_bounds__(256, 1)
snn_base(const float* __restrict__ x, const float* __restrict__ W1,
         unsigned char* __restrict__ ws, float* __restrict__ out)
{
  __shared__ float lds[12288];

  const int tid = threadIdx.x;
  const int l   = tid & 63;
  const int w   = tid >> 6;
  const int lr  = l & 31;
  const int lg  = l >> 5;
  const int blk = blockIdx.x;
  const int g   = blk >> 5;
  const int r   = blk & 31;
  const int b0  = g * GBLK;

  unsigned char* sb  = ws + SB_OFF;
  unsigned*      bar = (unsigned*)(ws + BAR_OFF);
  const unsigned short* wb = (const unsigned short*)ws;

  int lay[3], hh[3], plA[3], plB[3];
  const unsigned short *wA[3], *wB[3];
#pragma unroll
  for (int i = 0; i < 3; ++i) {
    const int rt = r * 3 + i;
    lay[i] = rt >> 5;
    hh[i]  = (rt & 31) * 32;
    const size_t wl = (size_t)(hh[i] + lr) * KP + w * 256 + lg * 8;
    if (lay[i] == 0)      { wA[i] = wb + 0*W_SH + wl; wB[i] = wb;               plA[i] = 0; plB[i] = 0; }
    else if (lay[i] == 1) { wA[i] = wb + 1*W_SH + wl; wB[i] = wb + 2*W_SH + wl; plA[i] = 0; plB[i] = 1; }
    else                  { wA[i] = wb + 3*W_SH + wl; wB[i] = wb + 4*W_SH + wl; plA[i] = 1; plB[i] = 2; }
  }

  f32x16 v[3];
#pragma unroll
  for (int i = 0; i < 3; ++i)
#pragma unroll
    for (int j = 0; j < 16; ++j) v[i][j] = 0.f;

#pragma unroll 1
  for (int p = 0; p < Tt + 2; ++p) {
    const int srd = (p + 1) & 1;
    const int swr = p & 1;

#pragma unroll
    for (int i = 0; i < 3; ++i) {
      if (lay[i] != 0) continue;
      const int fh = tid & 31;
      const int fb = tid >> 5;
      float F0 = 0.f, F1 = 0.f, F2 = 0.f, F3 = 0.f;
      if (p < Tt) {
        const int hrow = hh[i] + fh;
        const float* xq0 = x + (size_t)(b0 + fb)      * (Lf * Tt) + p;
        const float* xq1 = x + (size_t)(b0 + fb + 8)  * (Lf * Tt) + p;
        const float* xq2 = x + (size_t)(b0 + fb + 16) * (Lf * Tt) + p;
        const float* xq3 = x + (size_t)(b0 + fb + 24) * (Lf * Tt) + p;
        const float* w1p = W1 + (size_t)hrow * Lf;
#pragma unroll
        for (int t = 0; t < Lf; ++t) {
          const float wv = (hrow < Hn) ? w1p[t] : 0.f;
          F0 = fmaf(xq0[(size_t)t * Tt], wv, F0);
          F1 = fmaf(xq1[(size_t)t * Tt], wv, F1);
          F2 = fmaf(xq2[(size_t)t * Tt], wv, F2);
          F3 = fmaf(xq3[(size_t)t * Tt], wv, F3);
        }
      }
      float* Fp = &lds[9216 + i * 1024 + fb * 32 + fh];
      Fp[0]       = F0;
      Fp[8 * 32]  = F1;
      Fp[16 * 32] = F2;
      Fp[24 * 32] = F3;
    }

    f32x16 acc[3];
#pragma unroll
    for (int i = 0; i < 3; ++i) {
#pragma unroll
      for (int j = 0; j < 16; ++j) acc[i][j] = 0.f;
      const size_t lanes = (size_t)lr * KP + w * 256 + lg * 8;
      const unsigned char* pA =
          sb + ((((size_t)srd * 3 + plA[i]) * NG + g) << 15) + lanes;
      stream16(acc[i], pA, wA[i]);
      if (lay[i] != 0) {
        const unsigned char* pB =
            sb + ((((size_t)srd * 3 + plB[i]) * NG + g) << 15) + lanes;
        stream16(acc[i], pB, wB[i]);
      }
    }

    if (w != 0) {
      float* dp = &lds[(w - 1) * 3 * 1024 + l];
#pragma unroll
      for (int i = 0; i < 3; ++i)
#pragma unroll
        for (int j = 0; j < 16; ++j) dp[i * 1024 + j * 64] = acc[i][j];
    }
    __syncthreads();

    if (w == 0) {
#pragma unroll
      for (int i = 0; i < 3; ++i) {
        unsigned char* o =
            sb + ((((size_t)swr * 3 + lay[i]) * NG + g) << 15) + hh[i] + lr;
#pragma unroll
        for (int j = 0; j < 16; ++j) {
          const int row = (j & 3) + 8 * (j >> 2) + 4 * lg;
          float a = acc[i][j];
#pragma unroll
          for (int ww = 0; ww < 3; ++ww)
            a += lds[(ww * 3 + i) * 1024 + j * 64 + l];
          const float F = (lay[i] == 0) ? lds[9216 + i * 1024 + row * 32 + lr] : 0.f;
          const float vn = 0.5f * (v[i][j] + a + F);
          const unsigned c = (vn >= 1.0f) ? 1u : 0u;
          v[i][j] = c ? 0.f : vn;
          asm volatile("global_store_byte %0, %1, off sc0 sc1"
                       :: "v"(o + (size_t)row * KP), "v"(c) : "memory");
        }
      }
    }

    asm volatile("s_waitcnt vmcnt(0)" ::: "memory");
    __syncthreads();
    if (tid == 0) {
      unsigned* cnt = bar + g * 32;
      unsigned* rel = bar + 512 + g * 32;
      unsigned old = __hip_atomic_fetch_add(cnt, 1u, __ATOMIC_RELAXED,
                                            __HIP_MEMORY_SCOPE_AGENT);
      if (old == (unsigned)(p + 1) * GBLK - 1u)
        __hip_atomic_store(rel, (unsigned)(p + 1), __ATOMIC_RELAXED,
                           __HIP_MEMORY_SCOPE_AGENT);
      while (__hip_atomic_load(rel, __ATOMIC_RELAXED,
                               __HIP_MEMORY_SCOPE_AGENT) < (unsigned)(p + 1))
        __builtin_amdgcn_s_sleep(1);
    }
    __syncthreads();
  }

  if (w == 0) {
#pragma unroll
    for (int i = 0; i < 3; ++i) {
      if (lay[i] != 2) continue;
      const int h = hh[i] + lr;
      if (h < Hn) {
#pragma unroll
        for (int j = 0; j < 16; ++j) {
          const int row = (j & 3) + 8 * (j >> 2) + 4 * lg;
          out[(size_t)(b0 + row) * Hn + h] = expf(v[i][j]);
        }
      }
    }
  }
}

// ======================= launcher =======================
extern "C" void kernel_launch(void* const* d_in, const int* in_sizes, int n_in,
                              void* d_out, int out_size, void* d_ws, size_t ws_size,
                              hipStream_t stream) {
  const float* x  = (const float*)d_in[0];
  const float* W1 = (const float*)d_in[1];
  const float* R1 = (const float*)d_in[2];
  const float* W2 = (const float*)d_in[3];
  const float* R2 = (const float*)d_in[4];
  const float* W3 = (const float*)d_in[5];
  const float* R3 = (const float*)d_in[6];
  float* out = (float*)d_out;
  unsigned char* ws = (unsigned char*)d_ws;
  (void)ws_size;   // layout identical to r10, which ran (needs 12.06 MB)

  // bf16 weight prep + zero spike slots / barrier area
  hipLaunchKernelGGL(prep_w, dim3(20480), dim3(256), 0, stream,
                     R1, W2, R2, W3, R3, ws);
  hipMemsetAsync(ws + SB_OFF, 0, SB_BYTES + 4096, stream);

  void* args[] = { (void*)&x, (void*)&W1, (void*)&ws, (void*)&out };

  // host-side occupancy gate (capture-safe) + launch-error fallback
  int nb = 0;
  hipError_t qe = hipOccupancyMaxActiveBlocksPerMultiprocessor(&nb, snn_fast, 256, 0);
  if (qe == hipSuccess && nb >= 1) {
    if (hipLaunchCooperativeKernel((const void*)snn_fast, dim3(NBLK), dim3(256),
                                   args, 0, stream) == hipSuccess)
      return;
  }
  // fallback: byte-exact r10 kernel (proven 15.4 ms)
  hipLaunchCooperativeKernel((const void*)snn_base, dim3(NBLK), dim3(256),
                             args, 0, stream);
}

// Round 13
// 15415.410 us; speedup vs baseline: 1.0025x; 1.0025x over previous
//
#include <hip/hip_runtime.h>

// Problem constants
constexpr int Bsz = 256, Lf = 14, Tt = 500, Hn = 1000;
constexpr int HP = 1024, KP = 1024;     // padded h/k extents
constexpr int NG = 8, GBLK = 32;        // 8 batch-groups (one per XCD) x 32 blocks
constexpr int NBLK = 256;

// d_ws layout (identical to r10/r12)
constexpr size_t W_MAT    = (size_t)HP * KP * 2;        // 2 MB bf16 per matrix
constexpr size_t W_SH     = (size_t)HP * KP;            // shorts per matrix
constexpr size_t SB_OFF   = 5 * W_MAT;                  // 10,485,760
// spike planes: [slot:2][layer:3][group:8][b:32][KP] bytes
constexpr size_t SB_BYTES = (size_t)2 * 3 * NG * GBLK * KP;  // 1,572,864
constexpr size_t BAR_OFF  = SB_OFF + SB_BYTES;

constexpr size_t DSM_BYTES = 98304;   // dynamic LDS: forces 1 block/CU

typedef __attribute__((ext_vector_type(8)))  short    short8;  // 8 bf16
typedef __attribute__((ext_vector_type(16))) float    f32x16;
typedef __attribute__((ext_vector_type(2)))  unsigned u32x2;
typedef __attribute__((ext_vector_type(4)))  unsigned u32x4v;

// ======================= prep kernel (bf16 weights) =======================
__device__ __forceinline__ unsigned short f2bf(float f) {
  unsigned u = __builtin_bit_cast(unsigned, f);
  unsigned r = (u + 0x7FFFu + ((u >> 16) & 1u)) >> 16;   // RNE
  return (unsigned short)r;
}

__global__ void prep_w(const float* __restrict__ R1, const float* __restrict__ W2,
                       const float* __restrict__ R2, const float* __restrict__ W3,
                       const float* __restrict__ R3, unsigned char* __restrict__ ws) {
  int id  = blockIdx.x * 256 + threadIdx.x;      // 5 * 2^20 threads
  int mat = id >> 20;
  int rem = id & 0xFFFFF;
  int h   = rem >> 10;
  int k   = rem & 1023;
  const float* src = (mat == 0) ? R1 : (mat == 1) ? W2 : (mat == 2) ? R2
                    : (mat == 3) ? W3 : R3;
  float v = (h < Hn && k < Hn) ? src[(size_t)h * Hn + k] : 0.f;
  ((unsigned short*)ws)[(size_t)mat * W_SH + (size_t)h * KP + k] = f2bf(v);
}

// ======================= shared helpers =======================
__device__ __forceinline__ short8 expand8(u32x2 d) {
  // 8 spike bytes (0/1) -> 8 bf16 (0.0/1.0). pair = b0 | b1<<16; *0x3F80.
  unsigned p0 = __umul24(((d[0] & 0xFFu)         | ((d[0] & 0xFF00u) << 8)), 0x3F80u);
  unsigned p1 = __umul24((((d[0] >> 16) & 0xFFu) | ((d[0] >> 24) << 16)),    0x3F80u);
  unsigned p2 = __umul24(((d[1] & 0xFFu)         | ((d[1] & 0xFF00u) << 8)), 0x3F80u);
  unsigned p3 = __umul24((((d[1] >> 16) & 0xFFu) | ((d[1] >> 24) << 16)),    0x3F80u);
  u32x4v u = {p0, p1, p2, p3};
  return __builtin_bit_cast(short8, u);
}

__device__ __forceinline__ f32x16 MF(short8 a, const unsigned short* wp, f32x16 c) {
  short8 b = *(const short8*)wp;
  return __builtin_amdgcn_mfma_f32_32x32x16_bf16(a, b, c, 0, 0, 0);
}

// device-scope (L3) atomic add, returns old
__device__ __forceinline__ unsigned aadd_sc1(unsigned* p) {
  unsigned old;
  asm volatile("global_atomic_add %0, %1, %2, off sc0 sc1\n\ts_waitcnt vmcnt(0)"
               : "=v"(old) : "v"(p), "v"(1u) : "memory");
  return old;
}
__device__ __forceinline__ void st_sc1(unsigned* p, unsigned v) {
  asm volatile("global_store_dword %0, %1, off sc0 sc1" :: "v"(p), "v"(v) : "memory");
}
__device__ __forceinline__ unsigned ld_sc1(unsigned* p) {
  unsigned v;
  asm volatile("global_load_dword %0, %1, off sc0 sc1\n\ts_waitcnt vmcnt(0)"
               : "=v"(v) : "v"(p) : "memory");
  return v;
}

// ---- L2-scope (intra-XCD) spike ops: sc0 only = bypass L1, served by XCD L2 ----
__device__ __forceinline__ void spk16_l2(const unsigned char* p, u32x2 d[16]) {
  asm volatile(
    "global_load_dwordx2 %0, %16, off sc0\n\t"
    "global_load_dwordx2 %1, %16, off offset:16 sc0\n\t"
    "global_load_dwordx2 %2, %16, off offset:32 sc0\n\t"
    "global_load_dwordx2 %3, %16, off offset:48 sc0\n\t"
    "global_load_dwordx2 %4, %16, off offset:64 sc0\n\t"
    "global_load_dwordx2 %5, %16, off offset:80 sc0\n\t"
    "global_load_dwordx2 %6, %16, off offset:96 sc0\n\t"
    "global_load_dwordx2 %7, %16, off offset:112 sc0\n\t"
    "global_load_dwordx2 %8, %16, off offset:128 sc0\n\t"
    "global_load_dwordx2 %9, %16, off offset:144 sc0\n\t"
    "global_load_dwordx2 %10, %16, off offset:160 sc0\n\t"
    "global_load_dwordx2 %11, %16, off offset:176 sc0\n\t"
    "global_load_dwordx2 %12, %16, off offset:192 sc0\n\t"
    "global_load_dwordx2 %13, %16, off offset:208 sc0\n\t"
    "global_load_dwordx2 %14, %16, off offset:224 sc0\n\t"
    "global_load_dwordx2 %15, %16, off offset:240 sc0"
    : "=&v"(d[0]), "=&v"(d[1]), "=&v"(d[2]), "=&v"(d[3]),
      "=&v"(d[4]), "=&v"(d[5]), "=&v"(d[6]), "=&v"(d[7]),
      "=&v"(d[8]), "=&v"(d[9]), "=&v"(d[10]), "=&v"(d[11]),
      "=&v"(d[12]), "=&v"(d[13]), "=&v"(d[14]), "=&v"(d[15])
    : "v"(p) : "memory");
}

// sc0 sc1 16-load burst (device-coherent; used by fallback kernel)
__device__ __forceinline__ void spk16_g(const unsigned char* p, u32x2 d[16]) {
  asm volatile(
    "global_load_dwordx2 %0, %16, off sc0 sc1\n\t"
    "global_load_dwordx2 %1, %16, off offset:16 sc0 sc1\n\t"
    "global_load_dwordx2 %2, %16, off offset:32 sc0 sc1\n\t"
    "global_load_dwordx2 %3, %16, off offset:48 sc0 sc1\n\t"
    "global_load_dwordx2 %4, %16, off offset:64 sc0 sc1\n\t"
    "global_load_dwordx2 %5, %16, off offset:80 sc0 sc1\n\t"
    "global_load_dwordx2 %6, %16, off offset:96 sc0 sc1\n\t"
    "global_load_dwordx2 %7, %16, off offset:112 sc0 sc1\n\t"
    "global_load_dwordx2 %8, %16, off offset:128 sc0 sc1\n\t"
    "global_load_dwordx2 %9, %16, off offset:144 sc0 sc1\n\t"
    "global_load_dwordx2 %10, %16, off offset:160 sc0 sc1\n\t"
    "global_load_dwordx2 %11, %16, off offset:176 sc0 sc1\n\t"
    "global_load_dwordx2 %12, %16, off offset:192 sc0 sc1\n\t"
    "global_load_dwordx2 %13, %16, off offset:208 sc0 sc1\n\t"
    "global_load_dwordx2 %14, %16, off offset:224 sc0 sc1\n\t"
    "global_load_dwordx2 %15, %16, off offset:240 sc0 sc1\n\t"
    "s_waitcnt vmcnt(0)"
    : "=&v"(d[0]), "=&v"(d[1]), "=&v"(d[2]), "=&v"(d[3]),
      "=&v"(d[4]), "=&v"(d[5]), "=&v"(d[6]), "=&v"(d[7]),
      "=&v"(d[8]), "=&v"(d[9]), "=&v"(d[10]), "=&v"(d[11]),
      "=&v"(d[12]), "=&v"(d[13]), "=&v"(d[14]), "=&v"(d[15])
    : "v"(p) : "memory");
}

__device__ __forceinline__ void stream16(f32x16& acc, const unsigned char* sp,
                                         const unsigned short* wp) {
  u32x2 d[16];
  spk16_g(sp, d);
  __builtin_amdgcn_sched_barrier(0);
#pragma unroll
  for (int kc = 0; kc < 16; ++kc)
    acc = MF(expand8(d[kc]), wp + kc * 16, acc);
}

// ======================= PRIMARY: snn_xcd =======================
__global__ void __launch_bounds__(256, 1)
snn_xcd(const float* __restrict__ x, const float* __restrict__ W1,
        unsigned char* __restrict__ ws, float* __restrict__ out)
{
  extern __shared__ float lds[];   // [0,9216): reduce; [9216,12288): F tiles
  __shared__ int rank_sh;

  const int tid = threadIdx.x;
  const int l   = tid & 63;
  const int w   = tid >> 6;       // wave 0..3 = k-quarter
  const int lr  = l & 31;         // A-row (b) / B-col (h)
  const int lg  = l >> 5;         // k lane-group

  // group = this block's physical XCD (all group members share one L2)
  unsigned xcd;
  asm("s_getreg_b32 %0, hwreg(HW_REG_XCC_ID)" : "=s"(xcd));
  const int g  = (int)(xcd & 7);
  const int b0 = g * GBLK;

  unsigned char* sb  = ws + SB_OFF;
  unsigned*      bar = (unsigned*)(ws + BAR_OFF);
  unsigned*      cnt = bar + (size_t)g * 32;        // 128 B per group
  unsigned*      rel = bar + (size_t)g * 32 + 16;   // separate 64B line
  unsigned*      rnk = bar + 256 + (size_t)g * 16;  // rank counters
  const unsigned short* wb = (const unsigned short*)ws;

  // rank within group: L3 atomic (memset-fresh each launch). With 1 block/CU
  // and 256 blocks on 256 CUs, each XCD hosts exactly 32 blocks -> ranks 0..31.
  if (tid == 0) rank_sh = (int)aadd_sc1(rnk);
  __syncthreads();
  const int r = rank_sh & 31;

  // 3 row-tiles per block (r10 mapping)
  int lay[3], hh[3];
  const unsigned short *wA[3], *wB[3];
#pragma unroll
  for (int i = 0; i < 3; ++i) {
    const int rt = r * 3 + i;
    lay[i] = rt >> 5;
    hh[i]  = (rt & 31) * 32;
    const size_t wl = (size_t)(hh[i] + lr) * KP + w * 256 + lg * 8;
    if (lay[i] == 0)      { wA[i] = wb + 0 * W_SH + wl; wB[i] = wb + 0 * W_SH + wl; }
    else if (lay[i] == 1) { wA[i] = wb + 1 * W_SH + wl; wB[i] = wb + 2 * W_SH + wl; }
    else                  { wA[i] = wb + 3 * W_SH + wl; wB[i] = wb + 4 * W_SH + wl; }
  }

  // ---- prologue: zero row r of all 6 spike plane-slots IN THIS XCD'S L2 ----
  // (overwrites any stale L2 lines from a previous graph replay)
#pragma unroll
  for (int ps = 0; ps < 6; ++ps) {
    unsigned char* zb = sb + (((size_t)ps * NG + g) << 15) + (size_t)r * KP
                        + (size_t)tid * 4;
    asm volatile("global_store_dword %0, %1, off sc0" :: "v"(zb), "v"(0u) : "memory");
  }
  asm volatile("s_waitcnt vmcnt(0)" ::: "memory");
  __syncthreads();
  if (tid == 0) {
    unsigned old = aadd_sc1(cnt);
    if (old == (unsigned)GBLK - 1u) st_sc1(rel, 1u);   // release #1 = prologue done
  }

  f32x16 v[3];
#pragma unroll
  for (int i = 0; i < 3; ++i)
#pragma unroll
    for (int j = 0; j < 16; ++j) v[i][j] = 0.f;

#pragma unroll 1
  for (int p = 0; p < Tt + 2; ++p) {
    const int srd = (p + 1) & 1;
    const int swr = p & 1;

    // ---- F = x@W1^T for layer-0 tiles (x-only; hoisted above the gate) ----
#pragma unroll
    for (int i = 0; i < 3; ++i) {
      if (lay[i] != 0) continue;            // uniform per block
      const int fh = tid & 31;
      const int fb = tid >> 5;
      float F0 = 0.f, F1 = 0.f, F2 = 0.f, F3 = 0.f;
      if (p < Tt) {
        const int hrow = hh[i] + fh;
        const float* xq0 = x + (size_t)(b0 + fb)      * (Lf * Tt) + p;
        const float* xq1 = x + (size_t)(b0 + fb + 8)  * (Lf * Tt) + p;
        const float* xq2 = x + (size_t)(b0 + fb + 16) * (Lf * Tt) + p;
        const float* xq3 = x + (size_t)(b0 + fb + 24) * (Lf * Tt) + p;
        const float* w1p = W1 + (size_t)hrow * Lf;
#pragma unroll
        for (int t = 0; t < Lf; ++t) {
          const float wv = (hrow < Hn) ? w1p[t] : 0.f;
          F0 = fmaf(xq0[(size_t)t * Tt], wv, F0);
          F1 = fmaf(xq1[(size_t)t * Tt], wv, F1);
          F2 = fmaf(xq2[(size_t)t * Tt], wv, F2);
          F3 = fmaf(xq3[(size_t)t * Tt], wv, F3);
        }
      }
      float* Fp = &lds[9216 + i * 1024 + fb * 32 + fh];
      Fp[0]       = F0;
      Fp[8 * 32]  = F1;
      Fp[16 * 32] = F2;
      Fp[24 * 32] = F3;
    }

    // ---- gate: group's previous phase fully complete (release >= p+1) ----
    if (tid == 0) {
      for (;;) {
        if (ld_sc1(rel) >= (unsigned)(p + 1)) break;
        __builtin_amdgcn_s_sleep(2);
      }
    }
    __syncthreads();

    // ---- spike loads: 3 planes from OWN XCD's L2 (sc0), one wait ----
    const size_t lanes = (size_t)lr * KP + w * 256 + lg * 8;
    u32x2 d0[16], d1[16], d2[16];
    spk16_l2(sb + ((((size_t)srd * 3 + 0) * NG + g) << 15) + lanes, d0);
    spk16_l2(sb + ((((size_t)srd * 3 + 1) * NG + g) << 15) + lanes, d1);
    spk16_l2(sb + ((((size_t)srd * 3 + 2) * NG + g) << 15) + lanes, d2);
    asm volatile("s_waitcnt vmcnt(0)" ::: "memory");
    __builtin_amdgcn_sched_barrier(0);

    // ---- MFMA: per-tile consumption from preloaded planes ----
    f32x16 acc[3];
#pragma unroll
    for (int i = 0; i < 3; ++i) {
#pragma unroll
      for (int j = 0; j < 16; ++j) acc[i][j] = 0.f;
      if (lay[i] == 0) {
#pragma unroll
        for (int kc = 0; kc < 16; ++kc)
          acc[i] = MF(expand8(d0[kc]), wA[i] + kc * 16, acc[i]);
      } else if (lay[i] == 1) {
#pragma unroll
        for (int kc = 0; kc < 16; ++kc) {
          acc[i] = MF(expand8(d0[kc]), wA[i] + kc * 16, acc[i]);
          acc[i] = MF(expand8(d1[kc]), wB[i] + kc * 16, acc[i]);
        }
      } else {
#pragma unroll
        for (int kc = 0; kc < 16; ++kc) {
          acc[i] = MF(expand8(d1[kc]), wA[i] + kc * 16, acc[i]);
          acc[i] = MF(expand8(d2[kc]), wB[i] + kc * 16, acc[i]);
        }
      }
    }

    // ---- cross-wave reduce ([j][lane] layout, conflict-free) ----
    if (w != 0) {
      float* dp = &lds[(w - 1) * 3 * 1024 + l];
#pragma unroll
      for (int i = 0; i < 3; ++i)
#pragma unroll
        for (int j = 0; j < 16; ++j) dp[i * 1024 + j * 64] = acc[i][j];
    }
    __syncthreads();

    if (w == 0) {
#pragma unroll
      for (int i = 0; i < 3; ++i) {
        unsigned char* o =
            sb + ((((size_t)swr * 3 + lay[i]) * NG + g) << 15) + hh[i] + lr;
#pragma unroll
        for (int j = 0; j < 16; ++j) {
          const int row = (j & 3) + 8 * (j >> 2) + 4 * lg;   // batch row
          float a = acc[i][j];
#pragma unroll
          for (int ww = 0; ww < 3; ++ww)
            a += lds[(ww * 3 + i) * 1024 + j * 64 + l];
          const float F = (lay[i] == 0) ? lds[9216 + i * 1024 + row * 32 + lr] : 0.f;
          const float vn = 0.5f * (v[i][j] + a + F);
          const unsigned c = (vn >= 1.0f) ? 1u : 0u;
          v[i][j] = c ? 0.f : vn;
          asm volatile("global_store_byte %0, %1, off sc0"   // L2-local store
                       :: "v"(o + (size_t)row * KP), "v"(c) : "memory");
        }
      }
    }

    // ---- arrive: spike stores drained -> count; last publishes release ----
    asm volatile("s_waitcnt vmcnt(0)" ::: "memory");
    __syncthreads();
    if (tid == 0) {
      unsigned old = aadd_sc1(cnt);
      if (old == (unsigned)(p + 2) * GBLK - 1u)
        st_sc1(rel, (unsigned)(p + 2));
    }
    __syncthreads();
  }

  // ---- output: exp(final v3) from layer-2 tiles ----
  if (w == 0) {
#pragma unroll
    for (int i = 0; i < 3; ++i) {
      if (lay[i] != 2) continue;
      const int h = hh[i] + lr;
      if (h < Hn) {
#pragma unroll
        for (int j = 0; j < 16; ++j) {
          const int row = (j & 3) + 8 * (j >> 2) + 4 * lg;
          out[(size_t)(b0 + row) * Hn + h] = expf(v[i][j]);
        }
      }
    }
  }
}

// ======================= FALLBACK: snn_base (r10 verbatim, proven) =======================
__global__ void __launch_bounds__(256, 1)
snn_base(const float* __restrict__ x, const float* __restrict__ W1,
         unsigned char* __restrict__ ws, float* __restrict__ out)
{
  __shared__ float slds[12288];

  const int tid = threadIdx.x;
  const int l   = tid & 63;
  const int w   = tid >> 6;
  const int lr  = l & 31;
  const int lg  = l >> 5;
  const int blk = blockIdx.x;
  const int g   = blk >> 5;
  const int r   = blk & 31;
  const int b0  = g * GBLK;

  unsigned char* sb  = ws + SB_OFF;
  unsigned*      bar = (unsigned*)(ws + BAR_OFF);
  const unsigned short* wb = (const unsigned short*)ws;

  int lay[3], hh[3], plA[3], plB[3];
  const unsigned short *wA[3], *wB[3];
#pragma unroll
  for (int i = 0; i < 3; ++i) {
    const int rt = r * 3 + i;
    lay[i] = rt >> 5;
    hh[i]  = (rt & 31) * 32;
    const size_t wl = (size_t)(hh[i] + lr) * KP + w * 256 + lg * 8;
    if (lay[i] == 0)      { wA[i] = wb + 0*W_SH + wl; wB[i] = wb;               plA[i] = 0; plB[i] = 0; }
    else if (lay[i] == 1) { wA[i] = wb + 1*W_SH + wl; wB[i] = wb + 2*W_SH + wl; plA[i] = 0; plB[i] = 1; }
    else                  { wA[i] = wb + 3*W_SH + wl; wB[i] = wb + 4*W_SH + wl; plA[i] = 1; plB[i] = 2; }
  }

  f32x16 v[3];
#pragma unroll
  for (int i = 0; i < 3; ++i)
#pragma unroll
    for (int j = 0; j < 16; ++j) v[i][j] = 0.f;

#pragma unroll 1
  for (int p = 0; p < Tt + 2; ++p) {
    const int srd = (p + 1) & 1;
    const int swr = p & 1;

#pragma unroll
    for (int i = 0; i < 3; ++i) {
      if (lay[i] != 0) continue;
      const int fh = tid & 31;
      const int fb = tid >> 5;
      float F0 = 0.f, F1 = 0.f, F2 = 0.f, F3 = 0.f;
      if (p < Tt) {
        const int hrow = hh[i] + fh;
        const float* xq0 = x + (size_t)(b0 + fb)      * (Lf * Tt) + p;
        const float* xq1 = x + (size_t)(b0 + fb + 8)  * (Lf * Tt) + p;
        const float* xq2 = x + (size_t)(b0 + fb + 16) * (Lf * Tt) + p;
        const float* xq3 = x + (size_t)(b0 + fb + 24) * (Lf * Tt) + p;
        const float* w1p = W1 + (size_t)hrow * Lf;
#pragma unroll
        for (int t = 0; t < Lf; ++t) {
          const float wv = (hrow < Hn) ? w1p[t] : 0.f;
          F0 = fmaf(xq0[(size_t)t * Tt], wv, F0);
          F1 = fmaf(xq1[(size_t)t * Tt], wv, F1);
          F2 = fmaf(xq2[(size_t)t * Tt], wv, F2);
          F3 = fmaf(xq3[(size_t)t * Tt], wv, F3);
        }
      }
      float* Fp = &slds[9216 + i * 1024 + fb * 32 + fh];
      Fp[0]       = F0;
      Fp[8 * 32]  = F1;
      Fp[16 * 32] = F2;
      Fp[24 * 32] = F3;
    }

    f32x16 acc[3];
#pragma unroll
    for (int i = 0; i < 3; ++i) {
#pragma unroll
      for (int j = 0; j < 16; ++j) acc[i][j] = 0.f;
      const size_t lanes = (size_t)lr * KP + w * 256 + lg * 8;
      const unsigned char* pA =
          sb + ((((size_t)srd * 3 + plA[i]) * NG + g) << 15) + lanes;
      stream16(acc[i], pA, wA[i]);
      if (lay[i] != 0) {
        const unsigned char* pB =
            sb + ((((size_t)srd * 3 + plB[i]) * NG + g) << 15) + lanes;
        stream16(acc[i], pB, wB[i]);
      }
    }

    if (w != 0) {
      float* dp = &slds[(w - 1) * 3 * 1024 + l];
#pragma unroll
      for (int i = 0; i < 3; ++i)
#pragma unroll
        for (int j = 0; j < 16; ++j) dp[i * 1024 + j * 64] = acc[i][j];
    }
    __syncthreads();

    if (w == 0) {
#pragma unroll
      for (int i = 0; i < 3; ++i) {
        unsigned char* o =
            sb + ((((size_t)swr * 3 + lay[i]) * NG + g) << 15) + hh[i] + lr;
#pragma unroll
        for (int j = 0; j < 16; ++j) {
          const int row = (j & 3) + 8 * (j >> 2) + 4 * lg;
          float a = acc[i][j];
#pragma unroll
          for (int ww = 0; ww < 3; ++ww)
            a += slds[(ww * 3 + i) * 1024 + j * 64 + l];
          const float F = (lay[i] == 0) ? slds[9216 + i * 1024 + row * 32 + lr] : 0.f;
          const float vn = 0.5f * (v[i][j] + a + F);
          const unsigned c = (vn >= 1.0f) ? 1u : 0u;
          v[i][j] = c ? 0.f : vn;
          asm volatile("global_store_byte %0, %1, off sc0 sc1"
                       :: "v"(o + (size_t)row * KP), "v"(c) : "memory");
        }
      }
    }

    asm volatile("s_waitcnt vmcnt(0)" ::: "memory");
    __syncthreads();
    if (tid == 0) {
      unsigned* cnt = bar + g * 32;
      unsigned* rel = bar + 512 + g * 32;
      unsigned old = __hip_atomic_fetch_add(cnt, 1u, __ATOMIC_RELAXED,
                                            __HIP_MEMORY_SCOPE_AGENT);
      if (old == (unsigned)(p + 1) * GBLK - 1u)
        __hip_atomic_store(rel, (unsigned)(p + 1), __ATOMIC_RELAXED,
                           __HIP_MEMORY_SCOPE_AGENT);
      while (__hip_atomic_load(rel, __ATOMIC_RELAXED,
                               __HIP_MEMORY_SCOPE_AGENT) < (unsigned)(p + 1))
        __builtin_amdgcn_s_sleep(1);
    }
    __syncthreads();
  }

  if (w == 0) {
#pragma unroll
    for (int i = 0; i < 3; ++i) {
      if (lay[i] != 2) continue;
      const int h = hh[i] + lr;
      if (h < Hn) {
#pragma unroll
        for (int j = 0; j < 16; ++j) {
          const int row = (j & 3) + 8 * (j >> 2) + 4 * lg;
          out[(size_t)(b0 + row) * Hn + h] = expf(v[i][j]);
        }
      }
    }
  }
}

// ======================= launcher =======================
extern "C" void kernel_launch(void* const* d_in, const int* in_sizes, int n_in,
                              void* d_out, int out_size, void* d_ws, size_t ws_size,
                              hipStream_t stream) {
  const float* x  = (const float*)d_in[0];
  const float* W1 = (const float*)d_in[1];
  const float* R1 = (const float*)d_in[2];
  const float* W2 = (const float*)d_in[3];
  const float* R2 = (const float*)d_in[4];
  const float* W3 = (const float*)d_in[5];
  const float* R3 = (const float*)d_in[6];
  float* out = (float*)d_out;
  unsigned char* ws = (unsigned char*)d_ws;
  (void)ws_size;   // layout identical to r10/r12 (12.06 MB, proven present)

  hipFuncSetAttribute((const void*)snn_xcd,
                      hipFuncAttributeMaxDynamicSharedMemorySize, (int)DSM_BYTES);

  // bf16 weight prep + zero spike slots / barrier area (every launch/replay)
  hipLaunchKernelGGL(prep_w, dim3(20480), dim3(256), 0, stream,
                     R1, W2, R2, W3, R3, ws);
  hipMemsetAsync(ws + SB_OFF, 0, SB_BYTES + 4096, stream);

  void* args[] = { (void*)&x, (void*)&W1, (void*)&ws, (void*)&out };

  // primary: XCD-local kernel (needs exactly 1 block/CU -> 96KB dynamic LDS)
  int nb = 0;
  hipError_t qe = hipOccupancyMaxActiveBlocksPerMultiprocessor(&nb, snn_xcd, 256,
                                                               DSM_BYTES);
  if (qe == hipSuccess && nb == 1) {
    if (hipLaunchCooperativeKernel((const void*)snn_xcd, dim3(NBLK), dim3(256),
                                   args, DSM_BYTES, stream) == hipSuccess)
      return;
  }
  // fallback: r10 kernel (proven 15.4 ms)
  hipLaunchCooperativeKernel((const void*)snn_base, dim3(NBLK), dim3(256),
                             args, 0, stream);
}

// Round 14
// 13293.202 us; speedup vs baseline: 1.1625x; 1.1596x over previous
//
#include <hip/hip_runtime.h>

// Problem constants
constexpr int Bsz = 256, Lf = 14, Tt = 500, Hn = 1000;
constexpr int HP = 1024, KP = 1024;     // padded h/k extents
constexpr int NG = 8, GBLK = 32;        // 8 batch-groups of 32 blocks
constexpr int NBLK = 256;

// d_ws layout (identical to r10/r12)
constexpr size_t W_MAT    = (size_t)HP * KP * 2;        // 2 MB bf16 per matrix
constexpr size_t W_SH     = (size_t)HP * KP;            // shorts per matrix
constexpr size_t SB_OFF   = 5 * W_MAT;                  // 10,485,760
// spike planes: [slot:2][layer:3][group:8][b:32][KP] bytes
constexpr size_t SB_BYTES = (size_t)2 * 3 * NG * GBLK * KP;  // 1,572,864
constexpr size_t BAR_OFF  = SB_OFF + SB_BYTES;
constexpr size_t BAR_BYTES = 16384;   // 8 groups x 32 flags x 64 B

typedef __attribute__((ext_vector_type(8)))  short    short8;  // 8 bf16
typedef __attribute__((ext_vector_type(16))) float    f32x16;
typedef __attribute__((ext_vector_type(2)))  unsigned u32x2;
typedef __attribute__((ext_vector_type(4)))  unsigned u32x4v;

// ======================= prep kernel (bf16 weights) =======================
__device__ __forceinline__ unsigned short f2bf(float f) {
  unsigned u = __builtin_bit_cast(unsigned, f);
  unsigned r = (u + 0x7FFFu + ((u >> 16) & 1u)) >> 16;   // RNE
  return (unsigned short)r;
}

__global__ void prep_w(const float* __restrict__ R1, const float* __restrict__ W2,
                       const float* __restrict__ R2, const float* __restrict__ W3,
                       const float* __restrict__ R3, unsigned char* __restrict__ ws) {
  int id  = blockIdx.x * 256 + threadIdx.x;      // 5 * 2^20 threads
  int mat = id >> 20;
  int rem = id & 0xFFFFF;
  int h   = rem >> 10;
  int k   = rem & 1023;
  const float* src = (mat == 0) ? R1 : (mat == 1) ? W2 : (mat == 2) ? R2
                    : (mat == 3) ? W3 : R3;
  float v = (h < Hn && k < Hn) ? src[(size_t)h * Hn + k] : 0.f;
  ((unsigned short*)ws)[(size_t)mat * W_SH + (size_t)h * KP + k] = f2bf(v);
}

// ======================= shared helpers =======================
__device__ __forceinline__ short8 expand8(u32x2 d) {
  // 8 spike bytes (0/1) -> 8 bf16 (0.0/1.0). pair = b0 | b1<<16; *0x3F80.
  unsigned p0 = __umul24(((d[0] & 0xFFu)         | ((d[0] & 0xFF00u) << 8)), 0x3F80u);
  unsigned p1 = __umul24((((d[0] >> 16) & 0xFFu) | ((d[0] >> 24) << 16)),    0x3F80u);
  unsigned p2 = __umul24(((d[1] & 0xFFu)         | ((d[1] & 0xFF00u) << 8)), 0x3F80u);
  unsigned p3 = __umul24((((d[1] >> 16) & 0xFFu) | ((d[1] >> 24) << 16)),    0x3F80u);
  u32x4v u = {p0, p1, p2, p3};
  return __builtin_bit_cast(short8, u);
}

__device__ __forceinline__ f32x16 MF(short8 a, const unsigned short* wp, f32x16 c) {
  short8 b = *(const short8*)wp;
  return __builtin_amdgcn_mfma_f32_32x32x16_bf16(a, b, c, 0, 0, 0);
}

// 16 coherent dwordx2 spike loads, NO wait (burst building block).
__device__ __forceinline__ void spk16_nw(const unsigned char* p, u32x2 d[16]) {
  asm volatile(
    "global_load_dwordx2 %0, %16, off sc0 sc1\n\t"
    "global_load_dwordx2 %1, %16, off offset:16 sc0 sc1\n\t"
    "global_load_dwordx2 %2, %16, off offset:32 sc0 sc1\n\t"
    "global_load_dwordx2 %3, %16, off offset:48 sc0 sc1\n\t"
    "global_load_dwordx2 %4, %16, off offset:64 sc0 sc1\n\t"
    "global_load_dwordx2 %5, %16, off offset:80 sc0 sc1\n\t"
    "global_load_dwordx2 %6, %16, off offset:96 sc0 sc1\n\t"
    "global_load_dwordx2 %7, %16, off offset:112 sc0 sc1\n\t"
    "global_load_dwordx2 %8, %16, off offset:128 sc0 sc1\n\t"
    "global_load_dwordx2 %9, %16, off offset:144 sc0 sc1\n\t"
    "global_load_dwordx2 %10, %16, off offset:160 sc0 sc1\n\t"
    "global_load_dwordx2 %11, %16, off offset:176 sc0 sc1\n\t"
    "global_load_dwordx2 %12, %16, off offset:192 sc0 sc1\n\t"
    "global_load_dwordx2 %13, %16, off offset:208 sc0 sc1\n\t"
    "global_load_dwordx2 %14, %16, off offset:224 sc0 sc1\n\t"
    "global_load_dwordx2 %15, %16, off offset:240 sc0 sc1"
    : "=&v"(d[0]), "=&v"(d[1]), "=&v"(d[2]), "=&v"(d[3]),
      "=&v"(d[4]), "=&v"(d[5]), "=&v"(d[6]), "=&v"(d[7]),
      "=&v"(d[8]), "=&v"(d[9]), "=&v"(d[10]), "=&v"(d[11]),
      "=&v"(d[12]), "=&v"(d[13]), "=&v"(d[14]), "=&v"(d[15])
    : "v"(p) : "memory");
}

// 16 loads WITH wait (fallback kernel)
__device__ __forceinline__ void spk16(const unsigned char* p, u32x2 d[16]) {
  spk16_nw(p, d);
  asm volatile("s_waitcnt vmcnt(0)" ::: "memory");
}

__device__ __forceinline__ void stream16(f32x16& acc, const unsigned char* sp,
                                         const unsigned short* wp) {
  u32x2 d[16];
  spk16(sp, d);
  __builtin_amdgcn_sched_barrier(0);
#pragma unroll
  for (int kc = 0; kc < 16; ++kc)
    acc = MF(expand8(d[kc]), wp + kc * 16, acc);
}

// ======================= PRIMARY: snn_flag (r12 + RMW-free flag barrier) =======================
__global__ void __launch_bounds__(256, 1)
snn_flag(const float* __restrict__ x, const float* __restrict__ W1,
         unsigned char* __restrict__ ws, float* __restrict__ out)
{
  // [0,9216): reduce (3 waves x 3 tiles x 1024, [j][lane]); [9216,12288): F tiles
  __shared__ float lds[12288];

  const int tid = threadIdx.x;
  const int l   = tid & 63;
  const int w   = tid >> 6;       // wave 0..3 = k-quarter
  const int lr  = l & 31;         // A-row (b) / B-col (h)
  const int lg  = l >> 5;         // k lane-group
  const int blk = blockIdx.x;
  const int g   = blk >> 5;       // batch group (same-rank blocks share an XCD)
  const int r   = blk & 31;       // rank -> 3 row-tiles
  const int b0  = g * GBLK;

  unsigned char* sb  = ws + SB_OFF;
  unsigned*      bar = (unsigned*)(ws + BAR_OFF);
  // flag(g, r) on its own 64B line
  unsigned*      myflag   = bar + ((size_t)g * GBLK + r) * 16;
  unsigned*      lanef    = bar + ((size_t)g * GBLK + (l & 31)) * 16;
  const unsigned short* wb = (const unsigned short*)ws;

  // 3 row-tiles per block (r10/r12 mapping)
  int lay[3], hh[3];
  const unsigned short *wA[3], *wB[3];
#pragma unroll
  for (int i = 0; i < 3; ++i) {
    const int rt = r * 3 + i;
    lay[i] = rt >> 5;
    hh[i]  = (rt & 31) * 32;
    const size_t wl = (size_t)(hh[i] + lr) * KP + w * 256 + lg * 8;
    if (lay[i] == 0)      { wA[i] = wb + 0 * W_SH + wl; wB[i] = wb + 0 * W_SH + wl; }
    else if (lay[i] == 1) { wA[i] = wb + 1 * W_SH + wl; wB[i] = wb + 2 * W_SH + wl; }
    else                  { wA[i] = wb + 3 * W_SH + wl; wB[i] = wb + 4 * W_SH + wl; }
  }

  f32x16 v[3];
#pragma unroll
  for (int i = 0; i < 3; ++i)
#pragma unroll
    for (int j = 0; j < 16; ++j) v[i][j] = 0.f;

#pragma unroll 1
  for (int p = 0; p < Tt + 2; ++p) {
    const int srd = (p + 1) & 1;
    const int swr = p & 1;

    // ---- F = x@W1^T for layer-0 tiles (x-only; above the gate) ----
#pragma unroll
    for (int i = 0; i < 3; ++i) {
      if (lay[i] != 0) continue;            // uniform per block
      const int fh = tid & 31;
      const int fb = tid >> 5;
      float F0 = 0.f, F1 = 0.f, F2 = 0.f, F3 = 0.f;
      if (p < Tt) {
        const int hrow = hh[i] + fh;
        const float* xq0 = x + (size_t)(b0 + fb)      * (Lf * Tt) + p;
        const float* xq1 = x + (size_t)(b0 + fb + 8)  * (Lf * Tt) + p;
        const float* xq2 = x + (size_t)(b0 + fb + 16) * (Lf * Tt) + p;
        const float* xq3 = x + (size_t)(b0 + fb + 24) * (Lf * Tt) + p;
        const float* w1p = W1 + (size_t)hrow * Lf;
#pragma unroll
        for (int t = 0; t < Lf; ++t) {
          const float wv = (hrow < Hn) ? w1p[t] : 0.f;
          F0 = fmaf(xq0[(size_t)t * Tt], wv, F0);
          F1 = fmaf(xq1[(size_t)t * Tt], wv, F1);
          F2 = fmaf(xq2[(size_t)t * Tt], wv, F2);
          F3 = fmaf(xq3[(size_t)t * Tt], wv, F3);
        }
      }
      float* Fp = &lds[9216 + i * 1024 + fb * 32 + fh];
      Fp[0]       = F0;
      Fp[8 * 32]  = F1;
      Fp[16 * 32] = F2;
      Fp[24 * 32] = F3;
    }

    // ---- gate: all 32 group flags >= p (wave 0, lane-parallel: 1 RT/poll) ----
    if (tid < 64) {
      for (;;) {
        unsigned fv;
        asm volatile("global_load_dword %0, %1, off sc0 sc1\n\ts_waitcnt vmcnt(0)"
                     : "=v"(fv) : "v"(lanef) : "memory");
        if (__all(fv >= (unsigned)p)) break;
        __builtin_amdgcn_s_sleep(1);
      }
    }
    __syncthreads();

    // ---- spike loads: 3 planes, ONE round trip ----
    const size_t lanes = (size_t)lr * KP + w * 256 + lg * 8;
    u32x2 d0[16], d1[16], d2[16];
    spk16_nw(sb + ((((size_t)srd * 3 + 0) * NG + g) << 15) + lanes, d0);
    spk16_nw(sb + ((((size_t)srd * 3 + 1) * NG + g) << 15) + lanes, d1);
    spk16_nw(sb + ((((size_t)srd * 3 + 2) * NG + g) << 15) + lanes, d2);
    asm volatile("s_waitcnt vmcnt(0)" ::: "memory");
    __builtin_amdgcn_sched_barrier(0);

    // ---- MFMA: per-tile consumption from the preloaded planes ----
    f32x16 acc[3];
#pragma unroll
    for (int i = 0; i < 3; ++i) {
#pragma unroll
      for (int j = 0; j < 16; ++j) acc[i][j] = 0.f;
      if (lay[i] == 0) {
#pragma unroll
        for (int kc = 0; kc < 16; ++kc)
          acc[i] = MF(expand8(d0[kc]), wA[i] + kc * 16, acc[i]);
      } else if (lay[i] == 1) {
#pragma unroll
        for (int kc = 0; kc < 16; ++kc) {
          acc[i] = MF(expand8(d0[kc]), wA[i] + kc * 16, acc[i]);
          acc[i] = MF(expand8(d1[kc]), wB[i] + kc * 16, acc[i]);
        }
      } else {
#pragma unroll
        for (int kc = 0; kc < 16; ++kc) {
          acc[i] = MF(expand8(d1[kc]), wA[i] + kc * 16, acc[i]);
          acc[i] = MF(expand8(d2[kc]), wB[i] + kc * 16, acc[i]);
        }
      }
    }

    // ---- cross-wave reduce ([j][lane] layout, conflict-free) ----
    if (w != 0) {
      float* dp = &lds[(w - 1) * 3 * 1024 + l];
#pragma unroll
      for (int i = 0; i < 3; ++i)
#pragma unroll
        for (int j = 0; j < 16; ++j) dp[i * 1024 + j * 64] = acc[i][j];
    }
    __syncthreads();

    if (w == 0) {
#pragma unroll
      for (int i = 0; i < 3; ++i) {
        unsigned char* o =
            sb + ((((size_t)swr * 3 + lay[i]) * NG + g) << 15) + hh[i] + lr;
#pragma unroll
        for (int j = 0; j < 16; ++j) {
          const int row = (j & 3) + 8 * (j >> 2) + 4 * lg;   // batch row
          float a = acc[i][j];
#pragma unroll
          for (int ww = 0; ww < 3; ++ww)
            a += lds[(ww * 3 + i) * 1024 + j * 64 + l];
          const float F = (lay[i] == 0) ? lds[9216 + i * 1024 + row * 32 + lr] : 0.f;
          const float vn = 0.5f * (v[i][j] + a + F);
          const unsigned c = (vn >= 1.0f) ? 1u : 0u;
          v[i][j] = c ? 0.f : vn;
          asm volatile("global_store_byte %0, %1, off sc0 sc1"
                       :: "v"(o + (size_t)row * KP), "v"(c) : "memory");
        }
      }
    }

    // ---- arrive: drain spike stores, then plain flag store (NO RMW) ----
    asm volatile("s_waitcnt vmcnt(0)" ::: "memory");
    __syncthreads();
    if (tid == 0) {
      asm volatile("global_store_dword %0, %1, off sc0 sc1"
                   :: "v"(myflag), "v"((unsigned)(p + 1)) : "memory");
    }
    __syncthreads();
  }

  // ---- output: exp(final v3) from layer-2 tiles ----
  if (w == 0) {
#pragma unroll
    for (int i = 0; i < 3; ++i) {
      if (lay[i] != 2) continue;
      const int h = hh[i] + lr;
      if (h < Hn) {
#pragma unroll
        for (int j = 0; j < 16; ++j) {
          const int row = (j & 3) + 8 * (j >> 2) + 4 * lg;
          out[(size_t)(b0 + row) * Hn + h] = expf(v[i][j]);
        }
      }
    }
  }
}

// ======================= FALLBACK: snn_base (r10 verbatim, proven) =======================
__global__ void __launch_bounds__(256, 1)
snn_base(const float* __restrict__ x, const float* __restrict__ W1,
         unsigned char* __restrict__ ws, float* __restrict__ out)
{
  __shared__ float slds[12288];

  const int tid = threadIdx.x;
  const int l   = tid & 63;
  const int w   = tid >> 6;
  const int lr  = l & 31;
  const int lg  = l >> 5;
  const int blk = blockIdx.x;
  const int g   = blk >> 5;
  const int r   = blk & 31;
  const int b0  = g * GBLK;

  unsigned char* sb  = ws + SB_OFF;
  unsigned*      bar = (unsigned*)(ws + BAR_OFF);
  const unsigned short* wb = (const unsigned short*)ws;

  int lay[3], hh[3], plA[3], plB[3];
  const unsigned short *wA[3], *wB[3];
#pragma unroll
  for (int i = 0; i < 3; ++i) {
    const int rt = r * 3 + i;
    lay[i] = rt >> 5;
    hh[i]  = (rt & 31) * 32;
    const size_t wl = (size_t)(hh[i] + lr) * KP + w * 256 + lg * 8;
    if (lay[i] == 0)      { wA[i] = wb + 0*W_SH + wl; wB[i] = wb;               plA[i] = 0; plB[i] = 0; }
    else if (lay[i] == 1) { wA[i] = wb + 1*W_SH + wl; wB[i] = wb + 2*W_SH + wl; plA[i] = 0; plB[i] = 1; }
    else                  { wA[i] = wb + 3*W_SH + wl; wB[i] = wb + 4*W_SH + wl; plA[i] = 1; plB[i] = 2; }
  }

  f32x16 v[3];
#pragma unroll
  for (int i = 0; i < 3; ++i)
#pragma unroll
    for (int j = 0; j < 16; ++j) v[i][j] = 0.f;

#pragma unroll 1
  for (int p = 0; p < Tt + 2; ++p) {
    const int srd = (p + 1) & 1;
    const int swr = p & 1;

#pragma unroll
    for (int i = 0; i < 3; ++i) {
      if (lay[i] != 0) continue;
      const int fh = tid & 31;
      const int fb = tid >> 5;
      float F0 = 0.f, F1 = 0.f, F2 = 0.f, F3 = 0.f;
      if (p < Tt) {
        const int hrow = hh[i] + fh;
        const float* xq0 = x + (size_t)(b0 + fb)      * (Lf * Tt) + p;
        const float* xq1 = x + (size_t)(b0 + fb + 8)  * (Lf * Tt) + p;
        const float* xq2 = x + (size_t)(b0 + fb + 16) * (Lf * Tt) + p;
        const float* xq3 = x + (size_t)(b0 + fb + 24) * (Lf * Tt) + p;
        const float* w1p = W1 + (size_t)hrow * Lf;
#pragma unroll
        for (int t = 0; t < Lf; ++t) {
          const float wv = (hrow < Hn) ? w1p[t] : 0.f;
          F0 = fmaf(xq0[(size_t)t * Tt], wv, F0);
          F1 = fmaf(xq1[(size_t)t * Tt], wv, F1);
          F2 = fmaf(xq2[(size_t)t * Tt], wv, F2);
          F3 = fmaf(xq3[(size_t)t * Tt], wv, F3);
        }
      }
      float* Fp = &slds[9216 + i * 1024 + fb * 32 + fh];
      Fp[0]       = F0;
      Fp[8 * 32]  = F1;
      Fp[16 * 32] = F2;
      Fp[24 * 32] = F3;
    }

    f32x16 acc[3];
#pragma unroll
    for (int i = 0; i < 3; ++i) {
#pragma unroll
      for (int j = 0; j < 16; ++j) acc[i][j] = 0.f;
      const size_t lanes = (size_t)lr * KP + w * 256 + lg * 8;
      const unsigned char* pA =
          sb + ((((size_t)srd * 3 + plA[i]) * NG + g) << 15) + lanes;
      stream16(acc[i], pA, wA[i]);
      if (lay[i] != 0) {
        const unsigned char* pB =
            sb + ((((size_t)srd * 3 + plB[i]) * NG + g) << 15) + lanes;
        stream16(acc[i], pB, wB[i]);
      }
    }

    if (w != 0) {
      float* dp = &slds[(w - 1) * 3 * 1024 + l];
#pragma unroll
      for (int i = 0; i < 3; ++i)
#pragma unroll
        for (int j = 0; j < 16; ++j) dp[i * 1024 + j * 64] = acc[i][j];
    }
    __syncthreads();

    if (w == 0) {
#pragma unroll
      for (int i = 0; i < 3; ++i) {
        unsigned char* o =
            sb + ((((size_t)swr * 3 + lay[i]) * NG + g) << 15) + hh[i] + lr;
#pragma unroll
        for (int j = 0; j < 16; ++j) {
          const int row = (j & 3) + 8 * (j >> 2) + 4 * lg;
          float a = acc[i][j];
#pragma unroll
          for (int ww = 0; ww < 3; ++ww)
            a += slds[(ww * 3 + i) * 1024 + j * 64 + l];
          const float F = (lay[i] == 0) ? slds[9216 + i * 1024 + row * 32 + lr] : 0.f;
          const float vn = 0.5f * (v[i][j] + a + F);
          const unsigned c = (vn >= 1.0f) ? 1u : 0u;
          v[i][j] = c ? 0.f : vn;
          asm volatile("global_store_byte %0, %1, off sc0 sc1"
                       :: "v"(o + (size_t)row * KP), "v"(c) : "memory");
        }
      }
    }

    asm volatile("s_waitcnt vmcnt(0)" ::: "memory");
    __syncthreads();
    if (tid == 0) {
      unsigned* cnt = bar + g * 32;
      unsigned* rel = bar + 2048 + g * 32;
      unsigned old = __hip_atomic_fetch_add(cnt, 1u, __ATOMIC_RELAXED,
                                            __HIP_MEMORY_SCOPE_AGENT);
      if (old == (unsigned)(p + 1) * GBLK - 1u)
        __hip_atomic_store(rel, (unsigned)(p + 1), __ATOMIC_RELAXED,
                           __HIP_MEMORY_SCOPE_AGENT);
      while (__hip_atomic_load(rel, __ATOMIC_RELAXED,
                               __HIP_MEMORY_SCOPE_AGENT) < (unsigned)(p + 1))
        __builtin_amdgcn_s_sleep(1);
    }
    __syncthreads();
  }

  if (w == 0) {
#pragma unroll
    for (int i = 0; i < 3; ++i) {
      if (lay[i] != 2) continue;
      const int h = hh[i] + lr;
      if (h < Hn) {
#pragma unroll
        for (int j = 0; j < 16; ++j) {
          const int row = (j & 3) + 8 * (j >> 2) + 4 * lg;
          out[(size_t)(b0 + row) * Hn + h] = expf(v[i][j]);
        }
      }
    }
  }
}

// ======================= launcher =======================
extern "C" void kernel_launch(void* const* d_in, const int* in_sizes, int n_in,
                              void* d_out, int out_size, void* d_ws, size_t ws_size,
                              hipStream_t stream) {
  const float* x  = (const float*)d_in[0];
  const float* W1 = (const float*)d_in[1];
  const float* R1 = (const float*)d_in[2];
  const float* W2 = (const float*)d_in[3];
  const float* R2 = (const float*)d_in[4];
  const float* W3 = (const float*)d_in[5];
  const float* R3 = (const float*)d_in[6];
  float* out = (float*)d_out;
  unsigned char* ws = (unsigned char*)d_ws;
  (void)ws_size;   // layout identical to r10/r12 (12.08 MB, proven present)

  // bf16 weight prep + zero spike slots / flag area (every launch/replay)
  hipLaunchKernelGGL(prep_w, dim3(20480), dim3(256), 0, stream,
                     R1, W2, R2, W3, R3, ws);
  hipMemsetAsync(ws + SB_OFF, 0, SB_BYTES + BAR_BYTES, stream);

  void* args[] = { (void*)&x, (void*)&W1, (void*)&ws, (void*)&out };

  if (hipLaunchCooperativeKernel((const void*)snn_flag, dim3(NBLK), dim3(256),
                                 args, 0, stream) == hipSuccess)
    return;
  // fallback: r10 kernel (proven 15.4 ms)
  hipLaunchCooperativeKernel((const void*)snn_base, dim3(NBLK), dim3(256),
                             args, 0, stream);
}

// Round 16
// 10320.408 us; speedup vs baseline: 1.4974x; 1.2881x over previous
//
#include <hip/hip_runtime.h>

// Problem constants
constexpr int Bsz = 256, Lf = 14, Tt = 500, Hn = 1000;
constexpr int HP = 1024, KP = 1024;     // padded h/k extents
constexpr int NG = 8, GBLK = 32;        // 8 batch-groups of 32 blocks
constexpr int NBLK = 256;

// d_ws layout (region sizes identical to r10..r14)
constexpr size_t W_MAT    = (size_t)HP * KP * 2;        // 2 MB bf16 per matrix
constexpr size_t W_SH     = (size_t)HP * KP;            // shorts per matrix
constexpr size_t SB_OFF   = 5 * W_MAT;                  // 10,485,760
constexpr size_t SB_BYTES = (size_t)2 * 3 * NG * GBLK * KP;  // 1,572,864
constexpr size_t BAR_OFF  = SB_OFF + SB_BYTES;
constexpr size_t BAR_BYTES = 16384;   // 8 groups x 32 flags x 64 B

// PRIMARY bitplane geometry (first 192.5 KB of SB region):
//   bp[slot:2][layer:3][group:8] -> 4096 B each = 32 rows x 128 B of k-bits
// FALLBACK uses the old byte planes over the same (zeroed) region.

typedef __attribute__((ext_vector_type(8)))  short    short8;  // 8 bf16
typedef __attribute__((ext_vector_type(16))) float    f32x16;
typedef __attribute__((ext_vector_type(2)))  unsigned u32x2;
typedef __attribute__((ext_vector_type(4)))  unsigned u32x4v;

// ======================= prep kernel (bf16 weights) =======================
__device__ __forceinline__ unsigned short f2bf(float f) {
  unsigned u = __builtin_bit_cast(unsigned, f);
  unsigned r = (u + 0x7FFFu + ((u >> 16) & 1u)) >> 16;   // RNE
  return (unsigned short)r;
}

__global__ void prep_w(const float* __restrict__ R1, const float* __restrict__ W2,
                       const float* __restrict__ R2, const float* __restrict__ W3,
                       const float* __restrict__ R3, unsigned char* __restrict__ ws) {
  int id  = blockIdx.x * 256 + threadIdx.x;      // 5 * 2^20 threads
  int mat = id >> 20;
  int rem = id & 0xFFFFF;
  int h   = rem >> 10;
  int k   = rem & 1023;
  const float* src = (mat == 0) ? R1 : (mat == 1) ? W2 : (mat == 2) ? R2
                    : (mat == 3) ? W3 : R3;
  float v = (h < Hn && k < Hn) ? src[(size_t)h * Hn + k] : 0.f;
  ((unsigned short*)ws)[(size_t)mat * W_SH + (size_t)h * KP + k] = f2bf(v);
}

// ======================= shared helpers =======================
__device__ __forceinline__ f32x16 MF(short8 a, const unsigned short* wp, f32x16 c) {
  short8 b = *(const short8*)wp;
  return __builtin_amdgcn_mfma_f32_32x32x16_bf16(a, b, c, 0, 0, 0);
}

// 8 spike BITS -> 8 bf16 (0.0/1.0): pair word = b_even*0x3F80 + b_odd*0x3F800000
__device__ __forceinline__ short8 expandBits(unsigned bt) {
  unsigned r0 = (bt & 1u)        * 0x3F80u + (bt & 2u)        * 0x1FC00000u;
  unsigned r1 = ((bt >> 2) & 1u) * 0x3F80u + ((bt >> 2) & 2u) * 0x1FC00000u;
  unsigned r2 = ((bt >> 4) & 1u) * 0x3F80u + ((bt >> 4) & 2u) * 0x1FC00000u;
  unsigned r3 = ((bt >> 6) & 1u) * 0x3F80u + ((bt >> 6) & 2u) * 0x1FC00000u;
  u32x4v u = {r0, r1, r2, r3};
  return __builtin_bit_cast(short8, u);
}

// byte (kc*2+lg) of this lane's 32B bit-slice (kc compile-time, shl = lg*8)
__device__ __forceinline__ unsigned bsel(const u32x4v& a, const u32x4v& b,
                                         int kc, unsigned shl) {
  unsigned q = (kc < 8) ? a[(unsigned)(kc >> 1)] : b[(unsigned)((kc - 8) >> 1)];
  return (q >> (((kc & 1) << 4) + shl)) & 0xFFu;
}

// 3 bit-plane slices (32B each), one round trip
__device__ __forceinline__ void bits3(const unsigned char* p0,
    const unsigned char* p1, const unsigned char* p2,
    u32x4v& a0, u32x4v& b0, u32x4v& a1, u32x4v& b1, u32x4v& a2, u32x4v& b2) {
  asm volatile(
    "global_load_dwordx4 %0, %6, off sc0 sc1\n\t"
    "global_load_dwordx4 %1, %6, off offset:16 sc0 sc1\n\t"
    "global_load_dwordx4 %2, %7, off sc0 sc1\n\t"
    "global_load_dwordx4 %3, %7, off offset:16 sc0 sc1\n\t"
    "global_load_dwordx4 %4, %8, off sc0 sc1\n\t"
    "global_load_dwordx4 %5, %8, off offset:16 sc0 sc1\n\t"
    "s_waitcnt vmcnt(0)"
    : "=&v"(a0), "=&v"(b0), "=&v"(a1), "=&v"(b1), "=&v"(a2), "=&v"(b2)
    : "v"(p0), "v"(p1), "v"(p2) : "memory");
}

// --- fallback-only helpers (byte planes, r14 verbatim) ---
__device__ __forceinline__ short8 expand8(u32x2 d) {
  unsigned p0 = __umul24(((d[0] & 0xFFu)         | ((d[0] & 0xFF00u) << 8)), 0x3F80u);
  unsigned p1 = __umul24((((d[0] >> 16) & 0xFFu) | ((d[0] >> 24) << 16)),    0x3F80u);
  unsigned p2 = __umul24(((d[1] & 0xFFu)         | ((d[1] & 0xFF00u) << 8)), 0x3F80u);
  unsigned p3 = __umul24((((d[1] >> 16) & 0xFFu) | ((d[1] >> 24) << 16)),    0x3F80u);
  u32x4v u = {p0, p1, p2, p3};
  return __builtin_bit_cast(short8, u);
}
__device__ __forceinline__ void spk16_nw(const unsigned char* p, u32x2 d[16]) {
  asm volatile(
    "global_load_dwordx2 %0, %16, off sc0 sc1\n\t"
    "global_load_dwordx2 %1, %16, off offset:16 sc0 sc1\n\t"
    "global_load_dwordx2 %2, %16, off offset:32 sc0 sc1\n\t"
    "global_load_dwordx2 %3, %16, off offset:48 sc0 sc1\n\t"
    "global_load_dwordx2 %4, %16, off offset:64 sc0 sc1\n\t"
    "global_load_dwordx2 %5, %16, off offset:80 sc0 sc1\n\t"
    "global_load_dwordx2 %6, %16, off offset:96 sc0 sc1\n\t"
    "global_load_dwordx2 %7, %16, off offset:112 sc0 sc1\n\t"
    "global_load_dwordx2 %8, %16, off offset:128 sc0 sc1\n\t"
    "global_load_dwordx2 %9, %16, off offset:144 sc0 sc1\n\t"
    "global_load_dwordx2 %10, %16, off offset:160 sc0 sc1\n\t"
    "global_load_dwordx2 %11, %16, off offset:176 sc0 sc1\n\t"
    "global_load_dwordx2 %12, %16, off offset:192 sc0 sc1\n\t"
    "global_load_dwordx2 %13, %16, off offset:208 sc0 sc1\n\t"
    "global_load_dwordx2 %14, %16, off offset:224 sc0 sc1\n\t"
    "global_load_dwordx2 %15, %16, off offset:240 sc0 sc1"
    : "=&v"(d[0]), "=&v"(d[1]), "=&v"(d[2]), "=&v"(d[3]),
      "=&v"(d[4]), "=&v"(d[5]), "=&v"(d[6]), "=&v"(d[7]),
      "=&v"(d[8]), "=&v"(d[9]), "=&v"(d[10]), "=&v"(d[11]),
      "=&v"(d[12]), "=&v"(d[13]), "=&v"(d[14]), "=&v"(d[15])
    : "v"(p) : "memory");
}

// ======================= PRIMARY: snn_bits =======================
__global__ void __launch_bounds__(256, 1)
snn_bits(const float* __restrict__ x, const float* __restrict__ W1,
         unsigned char* __restrict__ ws, float* __restrict__ out)
{
  __shared__ float lds[12288];   // [0,9216) reduce; [9216,12288) F tiles

  const int tid = threadIdx.x;
  const int l   = tid & 63;
  const int w   = tid >> 6;       // wave 0..3 = k-quarter
  const int lr  = l & 31;         // A-row (b) / B-col (h)
  const int lg  = l >> 5;         // k lane-group
  const int blk = blockIdx.x;
  const int g   = blk >> 5;       // batch group
  const int r   = blk & 31;       // rank -> 3 row-tiles
  const int b0  = g * GBLK;
  const unsigned shl = (unsigned)lg * 8u;

  unsigned char* sb  = ws + SB_OFF;
  unsigned*      bar = (unsigned*)(ws + BAR_OFF);
  unsigned*      myflag = bar + ((size_t)g * GBLK + r) * 16;
  unsigned*      lanef  = bar + ((size_t)g * GBLK + (l & 31)) * 16;
  const unsigned short* wb = (const unsigned short*)ws;

  // 3 row-tiles per block (r10..r14 mapping)
  int lay[3], hh[3];
  const unsigned short *wA[3], *wB[3];
#pragma unroll
  for (int i = 0; i < 3; ++i) {
    const int rt = r * 3 + i;
    lay[i] = rt >> 5;
    hh[i]  = (rt & 31) * 32;
    const size_t wl = (size_t)(hh[i] + lr) * KP + w * 256 + lg * 8;
    if (lay[i] == 0)      { wA[i] = wb + 0 * W_SH + wl; wB[i] = wb + 0 * W_SH + wl; }
    else if (lay[i] == 1) { wA[i] = wb + 1 * W_SH + wl; wB[i] = wb + 2 * W_SH + wl; }
    else                  { wA[i] = wb + 3 * W_SH + wl; wB[i] = wb + 4 * W_SH + wl; }
  }

  f32x16 v[3];
#pragma unroll
  for (int i = 0; i < 3; ++i)
#pragma unroll
    for (int j = 0; j < 16; ++j) v[i][j] = 0.f;

#pragma unroll 1
  for (int p = 0; p < Tt + 2; ++p) {
    const int srd = (p + 1) & 1;
    const int swr = p & 1;

    // ---- F = x@W1^T for layer-0 tiles (x-only; above the gate) ----
#pragma unroll
    for (int i = 0; i < 3; ++i) {
      if (lay[i] != 0) continue;            // uniform per block
      const int fh = tid & 31;
      const int fb = tid >> 5;
      float F0 = 0.f, F1 = 0.f, F2 = 0.f, F3 = 0.f;
      if (p < Tt) {
        const int hrow = hh[i] + fh;
        const float* xq0 = x + (size_t)(b0 + fb)      * (Lf * Tt) + p;
        const float* xq1 = x + (size_t)(b0 + fb + 8)  * (Lf * Tt) + p;
        const float* xq2 = x + (size_t)(b0 + fb + 16) * (Lf * Tt) + p;
        const float* xq3 = x + (size_t)(b0 + fb + 24) * (Lf * Tt) + p;
        const float* w1p = W1 + (size_t)hrow * Lf;
#pragma unroll
        for (int t = 0; t < Lf; ++t) {
          const float wv = (hrow < Hn) ? w1p[t] : 0.f;
          F0 = fmaf(xq0[(size_t)t * Tt], wv, F0);
          F1 = fmaf(xq1[(size_t)t * Tt], wv, F1);
          F2 = fmaf(xq2[(size_t)t * Tt], wv, F2);
          F3 = fmaf(xq3[(size_t)t * Tt], wv, F3);
        }
      }
      float* Fp = &lds[9216 + i * 1024 + fb * 32 + fh];
      Fp[0]       = F0;
      Fp[8 * 32]  = F1;
      Fp[16 * 32] = F2;
      Fp[24 * 32] = F3;
    }

    // ---- gate: all 32 group flags >= p (wave 0, lane-parallel) ----
    if (tid < 64) {
      for (;;) {
        unsigned fv;
        asm volatile("global_load_dword %0, %1, off sc0 sc1\n\ts_waitcnt vmcnt(0)"
                     : "=v"(fv) : "v"(lanef) : "memory");
        if (__all(fv >= (unsigned)p)) break;
        __builtin_amdgcn_s_sleep(1);
      }
    }
    __syncthreads();

    // ---- spike BIT loads: 3 planes x 32B per lane, ONE round trip ----
    const size_t lslice = (size_t)lr * 128 + (size_t)w * 32;
    const unsigned char* p0 = sb + (((size_t)srd * 3 + 0) * NG + g) * 4096 + lslice;
    const unsigned char* p1 = sb + (((size_t)srd * 3 + 1) * NG + g) * 4096 + lslice;
    const unsigned char* p2 = sb + (((size_t)srd * 3 + 2) * NG + g) * 4096 + lslice;
    u32x4v qa0, qb0, qa1, qb1, qa2, qb2;
    bits3(p0, p1, p2, qa0, qb0, qa1, qb1, qa2, qb2);
    __builtin_amdgcn_sched_barrier(0);

    // ---- MFMA: per-tile consumption from bit slices ----
    f32x16 acc[3];
#pragma unroll
    for (int i = 0; i < 3; ++i) {
#pragma unroll
      for (int j = 0; j < 16; ++j) acc[i][j] = 0.f;
      if (lay[i] == 0) {
#pragma unroll
        for (int kc = 0; kc < 16; ++kc)
          acc[i] = MF(expandBits(bsel(qa0, qb0, kc, shl)), wA[i] + kc * 16, acc[i]);
      } else if (lay[i] == 1) {
#pragma unroll
        for (int kc = 0; kc < 16; ++kc) {
          acc[i] = MF(expandBits(bsel(qa0, qb0, kc, shl)), wA[i] + kc * 16, acc[i]);
          acc[i] = MF(expandBits(bsel(qa1, qb1, kc, shl)), wB[i] + kc * 16, acc[i]);
        }
      } else {
#pragma unroll
        for (int kc = 0; kc < 16; ++kc) {
          acc[i] = MF(expandBits(bsel(qa1, qb1, kc, shl)), wA[i] + kc * 16, acc[i]);
          acc[i] = MF(expandBits(bsel(qa2, qb2, kc, shl)), wB[i] + kc * 16, acc[i]);
        }
      }
    }

    // ---- cross-wave reduce ([j][lane] layout, conflict-free) ----
    if (w != 0) {
      float* dp = &lds[(w - 1) * 3 * 1024 + l];
#pragma unroll
      for (int i = 0; i < 3; ++i)
#pragma unroll
        for (int j = 0; j < 16; ++j) dp[i * 1024 + j * 64] = acc[i][j];
    }
    __syncthreads();

    if (w == 0) {
#pragma unroll
      for (int i = 0; i < 3; ++i) {
        unsigned char* ob = sb + (((size_t)swr * 3 + lay[i]) * NG + g) * 4096
                            + (hh[i] >> 3);
#pragma unroll
        for (int j = 0; j < 16; ++j) {
          const int row = (j & 3) + 8 * (j >> 2) + 4 * lg;   // per-lane batch row
          float a = acc[i][j];
#pragma unroll
          for (int ww = 0; ww < 3; ++ww)
            a += lds[(ww * 3 + i) * 1024 + j * 64 + l];
          const float F = (lay[i] == 0) ? lds[9216 + i * 1024 + row * 32 + lr] : 0.f;
          const float vn = 0.5f * (v[i][j] + a + F);
          const unsigned c = (vn >= 1.0f) ? 1u : 0u;
          v[i][j] = c ? 0.f : vn;
          // pack: lanes 0-31 = row (j&3)+8*(j>>2), lanes 32-63 = +4
          unsigned long long m = __ballot(c != 0u);
          if (l == 0) {
            const int r0 = (j & 3) + 8 * (j >> 2);
            asm volatile("global_store_dword %0, %1, off sc0 sc1"
                         :: "v"(ob + (size_t)r0 * 128), "v"((unsigned)m) : "memory");
            asm volatile("global_store_dword %0, %1, off sc0 sc1"
                         :: "v"(ob + (size_t)(r0 + 4) * 128),
                            "v"((unsigned)(m >> 32)) : "memory");
          }
        }
      }
    }

    // ---- arrive: drain spike stores, then plain flag store (no RMW) ----
    asm volatile("s_waitcnt vmcnt(0)" ::: "memory");
    __syncthreads();
    if (tid == 0) {
      asm volatile("global_store_dword %0, %1, off sc0 sc1"
                   :: "v"(myflag), "v"((unsigned)(p + 1)) : "memory");
    }
    __syncthreads();
  }

  // ---- output: exp(final v3) from layer-2 tiles ----
  if (w == 0) {
#pragma unroll
    for (int i = 0; i < 3; ++i) {
      if (lay[i] != 2) continue;
      const int h = hh[i] + lr;
      if (h < Hn) {
#pragma unroll
        for (int j = 0; j < 16; ++j) {
          const int row = (j & 3) + 8 * (j >> 2) + 4 * lg;
          out[(size_t)(b0 + row) * Hn + h] = expf(v[i][j]);
        }
      }
    }
  }
}

// ======================= FALLBACK: snn_flag (r14 verbatim, proven 13.3 ms) ===
__global__ void __launch_bounds__(256, 1)
snn_flag(const float* __restrict__ x, const float* __restrict__ W1,
         unsigned char* __restrict__ ws, float* __restrict__ out)
{
  __shared__ float lds[12288];

  const int tid = threadIdx.x;
  const int l   = tid & 63;
  const int w   = tid >> 6;
  const int lr  = l & 31;
  const int lg  = l >> 5;
  const int blk = blockIdx.x;
  const int g   = blk >> 5;
  const int r   = blk & 31;
  const int b0  = g * GBLK;

  unsigned char* sb  = ws + SB_OFF;
  unsigned*      bar = (unsigned*)(ws + BAR_OFF);
  unsigned*      myflag = bar + ((size_t)g * GBLK + r) * 16;
  unsigned*      lanef  = bar + ((size_t)g * GBLK + (l & 31)) * 16;
  const unsigned short* wb = (const unsigned short*)ws;

  int lay[3], hh[3];
  const unsigned short *wA[3], *wB[3];
#pragma unroll
  for (int i = 0; i < 3; ++i) {
    const int rt = r * 3 + i;
    lay[i] = rt >> 5;
    hh[i]  = (rt & 31) * 32;
    const size_t wl = (size_t)(hh[i] + lr) * KP + w * 256 + lg * 8;
    if (lay[i] == 0)      { wA[i] = wb + 0 * W_SH + wl; wB[i] = wb + 0 * W_SH + wl; }
    else if (lay[i] == 1) { wA[i] = wb + 1 * W_SH + wl; wB[i] = wb + 2 * W_SH + wl; }
    else                  { wA[i] = wb + 3 * W_SH + wl; wB[i] = wb + 4 * W_SH + wl; }
  }

  f32x16 v[3];
#pragma unroll
  for (int i = 0; i < 3; ++i)
#pragma unroll
    for (int j = 0; j < 16; ++j) v[i][j] = 0.f;

#pragma unroll 1
  for (int p = 0; p < Tt + 2; ++p) {
    const int srd = (p + 1) & 1;
    const int swr = p & 1;

#pragma unroll
    for (int i = 0; i < 3; ++i) {
      if (lay[i] != 0) continue;
      const int fh = tid & 31;
      const int fb = tid >> 5;
      float F0 = 0.f, F1 = 0.f, F2 = 0.f, F3 = 0.f;
      if (p < Tt) {
        const int hrow = hh[i] + fh;
        const float* xq0 = x + (size_t)(b0 + fb)      * (Lf * Tt) + p;
        const float* xq1 = x + (size_t)(b0 + fb + 8)  * (Lf * Tt) + p;
        const float* xq2 = x + (size_t)(b0 + fb + 16) * (Lf * Tt) + p;
        const float* xq3 = x + (size_t)(b0 + fb + 24) * (Lf * Tt) + p;
        const float* w1p = W1 + (size_t)hrow * Lf;
#pragma unroll
        for (int t = 0; t < Lf; ++t) {
          const float wv = (hrow < Hn) ? w1p[t] : 0.f;
          F0 = fmaf(xq0[(size_t)t * Tt], wv, F0);
          F1 = fmaf(xq1[(size_t)t * Tt], wv, F1);
          F2 = fmaf(xq2[(size_t)t * Tt], wv, F2);
          F3 = fmaf(xq3[(size_t)t * Tt], wv, F3);
        }
      }
      float* Fp = &lds[9216 + i * 1024 + fb * 32 + fh];
      Fp[0]       = F0;
      Fp[8 * 32]  = F1;
      Fp[16 * 32] = F2;
      Fp[24 * 32] = F3;
    }

    if (tid < 64) {
      for (;;) {
        unsigned fv;
        asm volatile("global_load_dword %0, %1, off sc0 sc1\n\ts_waitcnt vmcnt(0)"
                     : "=v"(fv) : "v"(lanef) : "memory");
        if (__all(fv >= (unsigned)p)) break;
        __builtin_amdgcn_s_sleep(1);
      }
    }
    __syncthreads();

    const size_t lanes = (size_t)lr * KP + w * 256 + lg * 8;
    u32x2 d0[16], d1[16], d2[16];
    spk16_nw(sb + ((((size_t)srd * 3 + 0) * NG + g) << 15) + lanes, d0);
    spk16_nw(sb + ((((size_t)srd * 3 + 1) * NG + g) << 15) + lanes, d1);
    spk16_nw(sb + ((((size_t)srd * 3 + 2) * NG + g) << 15) + lanes, d2);
    asm volatile("s_waitcnt vmcnt(0)" ::: "memory");
    __builtin_amdgcn_sched_barrier(0);

    f32x16 acc[3];
#pragma unroll
    for (int i = 0; i < 3; ++i) {
#pragma unroll
      for (int j = 0; j < 16; ++j) acc[i][j] = 0.f;
      if (lay[i] == 0) {
#pragma unroll
        for (int kc = 0; kc < 16; ++kc)
          acc[i] = MF(expand8(d0[kc]), wA[i] + kc * 16, acc[i]);
      } else if (lay[i] == 1) {
#pragma unroll
        for (int kc = 0; kc < 16; ++kc) {
          acc[i] = MF(expand8(d0[kc]), wA[i] + kc * 16, acc[i]);
          acc[i] = MF(expand8(d1[kc]), wB[i] + kc * 16, acc[i]);
        }
      } else {
#pragma unroll
        for (int kc = 0; kc < 16; ++kc) {
          acc[i] = MF(expand8(d1[kc]), wA[i] + kc * 16, acc[i]);
          acc[i] = MF(expand8(d2[kc]), wB[i] + kc * 16, acc[i]);
        }
      }
    }

    if (w != 0) {
      float* dp = &lds[(w - 1) * 3 * 1024 + l];
#pragma unroll
      for (int i = 0; i < 3; ++i)
#pragma unroll
        for (int j = 0; j < 16; ++j) dp[i * 1024 + j * 64] = acc[i][j];
    }
    __syncthreads();

    if (w == 0) {
#pragma unroll
      for (int i = 0; i < 3; ++i) {
        unsigned char* o =
            sb + ((((size_t)swr * 3 + lay[i]) * NG + g) << 15) + hh[i] + lr;
#pragma unroll
        for (int j = 0; j < 16; ++j) {
          const int row = (j & 3) + 8 * (j >> 2) + 4 * lg;
          float a = acc[i][j];
#pragma unroll
          for (int ww = 0; ww < 3; ++ww)
            a += lds[(ww * 3 + i) * 1024 + j * 64 + l];
          const float F = (lay[i] == 0) ? lds[9216 + i * 1024 + row * 32 + lr] : 0.f;
          const float vn = 0.5f * (v[i][j] + a + F);
          const unsigned c = (vn >= 1.0f) ? 1u : 0u;
          v[i][j] = c ? 0.f : vn;
          asm volatile("global_store_byte %0, %1, off sc0 sc1"
                       :: "v"(o + (size_t)row * KP), "v"(c) : "memory");
        }
      }
    }

    asm volatile("s_waitcnt vmcnt(0)" ::: "memory");
    __syncthreads();
    if (tid == 0) {
      asm volatile("global_store_dword %0, %1, off sc0 sc1"
                   :: "v"(myflag), "v"((unsigned)(p + 1)) : "memory");
    }
    __syncthreads();
  }

  if (w == 0) {
#pragma unroll
    for (int i = 0; i < 3; ++i) {
      if (lay[i] != 2) continue;
      const int h = hh[i] + lr;
      if (h < Hn) {
#pragma unroll
        for (int j = 0; j < 16; ++j) {
          const int row = (j & 3) + 8 * (j >> 2) + 4 * lg;
          out[(size_t)(b0 + row) * Hn + h] = expf(v[i][j]);
        }
      }
    }
  }
}

// ======================= launcher =======================
extern "C" void kernel_launch(void* const* d_in, const int* in_sizes, int n_in,
                              void* d_out, int out_size, void* d_ws, size_t ws_size,
                              hipStream_t stream) {
  const float* x  = (const float*)d_in[0];
  const float* W1 = (const float*)d_in[1];
  const float* R1 = (const float*)d_in[2];
  const float* W2 = (const float*)d_in[3];
  const float* R2 = (const float*)d_in[4];
  const float* W3 = (const float*)d_in[5];
  const float* R3 = (const float*)d_in[6];
  float* out = (float*)d_out;
  unsigned char* ws = (unsigned char*)d_ws;
  (void)ws_size;   // layout identical to r10..r14 (12.08 MB, proven present)

  // bf16 weight prep + zero spike region / flag area (every launch/replay)
  hipLaunchKernelGGL(prep_w, dim3(20480), dim3(256), 0, stream,
                     R1, W2, R2, W3, R3, ws);
  hipMemsetAsync(ws + SB_OFF, 0, SB_BYTES + BAR_BYTES, stream);

  void* args[] = { (void*)&x, (void*)&W1, (void*)&ws, (void*)&out };

  if (hipLaunchCooperativeKernel((const void*)snn_bits, dim3(NBLK), dim3(256),
                                 args, 0, stream) == hipSuccess)
    return;
  // fallback: r14 kernel (proven 13.3 ms)
  hipLaunchCooperativeKernel((const void*)snn_flag, dim3(NBLK), dim3(256),
                             args, 0, stream);
}

// Round 17
// 9298.055 us; speedup vs baseline: 1.6621x; 1.1100x over previous
//
#include <hip/hip_runtime.h>

// Problem constants
constexpr int Bsz = 256, Lf = 14, Tt = 500, Hn = 1000;
constexpr int HP = 1024, KP = 1024;     // padded h/k extents
constexpr int NG = 8, GBLK = 32;        // 8 batch-groups of 32 blocks
constexpr int NBLK = 256;

// d_ws layout (region sizes identical to r10..r16)
constexpr size_t W_MAT    = (size_t)HP * KP * 2;        // 2 MB bf16 per matrix
constexpr size_t W_SH     = (size_t)HP * KP;            // shorts per matrix
constexpr size_t SB_OFF   = 5 * W_MAT;                  // 10,485,760
constexpr size_t SB_BYTES = (size_t)2 * 3 * NG * GBLK * KP;  // 1,572,864
constexpr size_t BAR_OFF  = SB_OFF + SB_BYTES;
constexpr size_t BAR_BYTES = 16384;   // 8 groups x 32 flags x 64 B

// bitplane geometry: bp[slot:2][layer:3][group:8] -> 4096 B = 32 rows x 128 B

typedef __attribute__((ext_vector_type(8)))  short    short8;  // 8 bf16
typedef __attribute__((ext_vector_type(16))) float    f32x16;
typedef __attribute__((ext_vector_type(4)))  unsigned u32x4v;

// ======================= prep kernel (bf16 weights) =======================
__device__ __forceinline__ unsigned short f2bf(float f) {
  unsigned u = __builtin_bit_cast(unsigned, f);
  unsigned r = (u + 0x7FFFu + ((u >> 16) & 1u)) >> 16;   // RNE
  return (unsigned short)r;
}

__global__ void prep_w(const float* __restrict__ R1, const float* __restrict__ W2,
                       const float* __restrict__ R2, const float* __restrict__ W3,
                       const float* __restrict__ R3, unsigned char* __restrict__ ws) {
  int id  = blockIdx.x * 256 + threadIdx.x;      // 5 * 2^20 threads
  int mat = id >> 20;
  int rem = id & 0xFFFFF;
  int h   = rem >> 10;
  int k   = rem & 1023;
  const float* src = (mat == 0) ? R1 : (mat == 1) ? W2 : (mat == 2) ? R2
                    : (mat == 3) ? W3 : R3;
  float v = (h < Hn && k < Hn) ? src[(size_t)h * Hn + k] : 0.f;
  ((unsigned short*)ws)[(size_t)mat * W_SH + (size_t)h * KP + k] = f2bf(v);
}

// ======================= shared helpers =======================
__device__ __forceinline__ f32x16 MF(short8 a, const unsigned short* wp, f32x16 c) {
  short8 b = *(const short8*)wp;
  return __builtin_amdgcn_mfma_f32_32x32x16_bf16(a, b, c, 0, 0, 0);
}

// 8 spike BITS -> 8 bf16 (0.0/1.0)
__device__ __forceinline__ short8 expandBits(unsigned bt) {
  unsigned r0 = (bt & 1u)        * 0x3F80u + (bt & 2u)        * 0x1FC00000u;
  unsigned r1 = ((bt >> 2) & 1u) * 0x3F80u + ((bt >> 2) & 2u) * 0x1FC00000u;
  unsigned r2 = ((bt >> 4) & 1u) * 0x3F80u + ((bt >> 4) & 2u) * 0x1FC00000u;
  unsigned r3 = ((bt >> 6) & 1u) * 0x3F80u + ((bt >> 6) & 2u) * 0x1FC00000u;
  u32x4v u = {r0, r1, r2, r3};
  return __builtin_bit_cast(short8, u);
}

// byte (kc*2+lg) of this lane's 32B bit-slice
__device__ __forceinline__ unsigned bsel(const u32x4v& a, const u32x4v& b,
                                         int kc, unsigned shl) {
  unsigned q = (kc < 8) ? a[(unsigned)(kc >> 1)] : b[(unsigned)((kc - 8) >> 1)];
  return (q >> (((kc & 1) << 4) + shl)) & 0xFFu;
}

// 3 bit-plane slices (32B each), one round trip
__device__ __forceinline__ void bits3(const unsigned char* p0,
    const unsigned char* p1, const unsigned char* p2,
    u32x4v& a0, u32x4v& b0, u32x4v& a1, u32x4v& b1, u32x4v& a2, u32x4v& b2) {
  asm volatile(
    "global_load_dwordx4 %0, %6, off sc0 sc1\n\t"
    "global_load_dwordx4 %1, %6, off offset:16 sc0 sc1\n\t"
    "global_load_dwordx4 %2, %7, off sc0 sc1\n\t"
    "global_load_dwordx4 %3, %7, off offset:16 sc0 sc1\n\t"
    "global_load_dwordx4 %4, %8, off sc0 sc1\n\t"
    "global_load_dwordx4 %5, %8, off offset:16 sc0 sc1\n\t"
    "s_waitcnt vmcnt(0)"
    : "=&v"(a0), "=&v"(b0), "=&v"(a1), "=&v"(b1), "=&v"(a2), "=&v"(b2)
    : "v"(p0), "v"(p1), "v"(p2) : "memory");
}

// ============ shared kernel body (thresholded gate = template param) ========
// PIPE=1: per-lane threshold offsets (ring decoupling). PIPE=0: r16 barrier.
template <int PIPE>
__device__ __forceinline__ void snn_body(const float* __restrict__ x,
    const float* __restrict__ W1, unsigned char* __restrict__ ws,
    float* __restrict__ out, float* lds)
{
  const int tid = threadIdx.x;
  const int l   = tid & 63;
  const int w   = tid >> 6;       // wave 0..3 = k-quarter
  const int lr  = l & 31;         // A-row (b) / B-col (h)
  const int lg  = l >> 5;         // k lane-group
  const int blk = blockIdx.x;
  const int g   = blk >> 5;       // batch group
  const int r   = blk & 31;       // rank -> 3 row-tiles
  const int b0  = g * GBLK;
  const unsigned shl = (unsigned)lg * 8u;

  unsigned char* sb  = ws + SB_OFF;
  unsigned*      bar = (unsigned*)(ws + BAR_OFF);
  unsigned*      myflag = bar + ((size_t)g * GBLK + r) * 16;
  unsigned*      lanef  = bar + ((size_t)g * GBLK + (l & 31)) * 16;
  const unsigned short* wb = (const unsigned short*)ws;

  // 3 row-tiles per block (r10..r16 mapping)
  int lay[3], hh[3];
  const unsigned short *wA[3], *wB[3];
#pragma unroll
  for (int i = 0; i < 3; ++i) {
    const int rt = r * 3 + i;
    lay[i] = rt >> 5;
    hh[i]  = (rt & 31) * 32;
    const size_t wl = (size_t)(hh[i] + lr) * KP + w * 256 + lg * 8;
    if (lay[i] == 0)      { wA[i] = wb + 0 * W_SH + wl; wB[i] = wb + 0 * W_SH + wl; }
    else if (lay[i] == 1) { wA[i] = wb + 1 * W_SH + wl; wB[i] = wb + 2 * W_SH + wl; }
    else                  { wA[i] = wb + 3 * W_SH + wl; wB[i] = wb + 4 * W_SH + wl; }
  }

  // per-lane gate threshold offset (PIPE only):
  //   off = 0 if lane-block produces a plane we READ   (need flag >= p)
  //       = 1 if lane-block consumes a plane we WRITE  (need flag >= p-1)
  //       = BIG otherwise (always passes)
  unsigned off = 0;
  if (PIPE) {
    bool rdP[3] = {false, false, false}, wrP[3] = {false, false, false};
#pragma unroll
    for (int i = 0; i < 3; ++i) {
      if (lay[i] == 0)      { rdP[0] = true; wrP[0] = true; }
      else if (lay[i] == 1) { rdP[0] = true; rdP[1] = true; wrP[1] = true; }
      else                  { rdP[1] = true; rdP[2] = true; wrP[2] = true; }
    }
    const int lb = l & 31;   // lane's peer rank
    // producer ranges: P0=[0,10] P1=[10,21] P2=[21,31]
    const bool isP[3] = { lb <= 10, lb >= 10 && lb <= 21, lb >= 21 };
    // consumer ranges: C0=[0,21] C1=[10,31] C2=[21,31]
    const bool isC[3] = { lb <= 21, lb >= 10, lb >= 21 };
    bool prod = false, cons = false;
#pragma unroll
    for (int pl = 0; pl < 3; ++pl) {
      prod |= rdP[pl] && isP[pl];
      cons |= wrP[pl] && isC[pl];
    }
    off = prod ? 0u : (cons ? 1u : 0x40000000u);
  }

  f32x16 v[3];
#pragma unroll
  for (int i = 0; i < 3; ++i)
#pragma unroll
    for (int j = 0; j < 16; ++j) v[i][j] = 0.f;

#pragma unroll 1
  for (int p = 0; p < Tt + 2; ++p) {
    const int srd = (p + 1) & 1;
    const int swr = p & 1;

    // ---- F = x@W1^T for layer-0 tiles (x-only; above the gate) ----
#pragma unroll
    for (int i = 0; i < 3; ++i) {
      if (lay[i] != 0) continue;            // uniform per block
      const int fh = tid & 31;
      const int fb = tid >> 5;
      float F0 = 0.f, F1 = 0.f, F2 = 0.f, F3 = 0.f;
      if (p < Tt) {
        const int hrow = hh[i] + fh;
        const float* xq0 = x + (size_t)(b0 + fb)      * (Lf * Tt) + p;
        const float* xq1 = x + (size_t)(b0 + fb + 8)  * (Lf * Tt) + p;
        const float* xq2 = x + (size_t)(b0 + fb + 16) * (Lf * Tt) + p;
        const float* xq3 = x + (size_t)(b0 + fb + 24) * (Lf * Tt) + p;
        const float* w1p = W1 + (size_t)hrow * Lf;
#pragma unroll
        for (int t = 0; t < Lf; ++t) {
          const float wv = (hrow < Hn) ? w1p[t] : 0.f;
          F0 = fmaf(xq0[(size_t)t * Tt], wv, F0);
          F1 = fmaf(xq1[(size_t)t * Tt], wv, F1);
          F2 = fmaf(xq2[(size_t)t * Tt], wv, F2);
          F3 = fmaf(xq3[(size_t)t * Tt], wv, F3);
        }
      }
      float* Fp = &lds[9216 + i * 1024 + fb * 32 + fh];
      Fp[0]       = F0;
      Fp[8 * 32]  = F1;
      Fp[16 * 32] = F2;
      Fp[24 * 32] = F3;
    }

    // ---- gate: thresholded per-lane flag poll (wave 0, one RT/poll) ----
    if (tid < 64) {
      for (;;) {
        unsigned fv;
        asm volatile("global_load_dword %0, %1, off sc0 sc1\n\ts_waitcnt vmcnt(0)"
                     : "=v"(fv) : "v"(lanef) : "memory");
        if (__all(fv + off >= (unsigned)p)) break;
        __builtin_amdgcn_s_sleep(1);
      }
    }
    __syncthreads();

    // ---- spike BIT loads: 3 planes x 32B per lane, ONE round trip ----
    const size_t lslice = (size_t)lr * 128 + (size_t)w * 32;
    const unsigned char* p0 = sb + (((size_t)srd * 3 + 0) * NG + g) * 4096 + lslice;
    const unsigned char* p1 = sb + (((size_t)srd * 3 + 1) * NG + g) * 4096 + lslice;
    const unsigned char* p2 = sb + (((size_t)srd * 3 + 2) * NG + g) * 4096 + lslice;
    u32x4v qa0, qb0, qa1, qb1, qa2, qb2;
    bits3(p0, p1, p2, qa0, qb0, qa1, qb1, qa2, qb2);
    __builtin_amdgcn_sched_barrier(0);

    // ---- MFMA: per-tile consumption from bit slices ----
    f32x16 acc[3];
#pragma unroll
    for (int i = 0; i < 3; ++i) {
#pragma unroll
      for (int j = 0; j < 16; ++j) acc[i][j] = 0.f;
      if (lay[i] == 0) {
#pragma unroll
        for (int kc = 0; kc < 16; ++kc)
          acc[i] = MF(expandBits(bsel(qa0, qb0, kc, shl)), wA[i] + kc * 16, acc[i]);
      } else if (lay[i] == 1) {
#pragma unroll
        for (int kc = 0; kc < 16; ++kc) {
          acc[i] = MF(expandBits(bsel(qa0, qb0, kc, shl)), wA[i] + kc * 16, acc[i]);
          acc[i] = MF(expandBits(bsel(qa1, qb1, kc, shl)), wB[i] + kc * 16, acc[i]);
        }
      } else {
#pragma unroll
        for (int kc = 0; kc < 16; ++kc) {
          acc[i] = MF(expandBits(bsel(qa1, qb1, kc, shl)), wA[i] + kc * 16, acc[i]);
          acc[i] = MF(expandBits(bsel(qa2, qb2, kc, shl)), wB[i] + kc * 16, acc[i]);
        }
      }
    }

    // ---- cross-wave reduce ([j][lane] layout, conflict-free) ----
    if (w != 0) {
      float* dp = &lds[(w - 1) * 3 * 1024 + l];
#pragma unroll
      for (int i = 0; i < 3; ++i)
#pragma unroll
        for (int j = 0; j < 16; ++j) dp[i * 1024 + j * 64] = acc[i][j];
    }
    __syncthreads();

    if (w == 0) {
#pragma unroll
      for (int i = 0; i < 3; ++i) {
        unsigned char* ob = sb + (((size_t)swr * 3 + lay[i]) * NG + g) * 4096
                            + (hh[i] >> 3);
#pragma unroll
        for (int j = 0; j < 16; ++j) {
          const int row = (j & 3) + 8 * (j >> 2) + 4 * lg;   // per-lane batch row
          float a = acc[i][j];
#pragma unroll
          for (int ww = 0; ww < 3; ++ww)
            a += lds[(ww * 3 + i) * 1024 + j * 64 + l];
          const float F = (lay[i] == 0) ? lds[9216 + i * 1024 + row * 32 + lr] : 0.f;
          const float vn = 0.5f * (v[i][j] + a + F);
          const unsigned c = (vn >= 1.0f) ? 1u : 0u;
          v[i][j] = c ? 0.f : vn;
          unsigned long long m = __ballot(c != 0u);
          if (l == 0) {
            const int r0 = (j & 3) + 8 * (j >> 2);
            asm volatile("global_store_dword %0, %1, off sc0 sc1"
                         :: "v"(ob + (size_t)r0 * 128), "v"((unsigned)m) : "memory");
            asm volatile("global_store_dword %0, %1, off sc0 sc1"
                         :: "v"(ob + (size_t)(r0 + 4) * 128),
                            "v"((unsigned)(m >> 32)) : "memory");
          }
        }
      }
    }

    // ---- arrive: drain spike stores, then plain flag store (no RMW) ----
    asm volatile("s_waitcnt vmcnt(0)" ::: "memory");
    __syncthreads();
    if (tid == 0) {
      asm volatile("global_store_dword %0, %1, off sc0 sc1"
                   :: "v"(myflag), "v"((unsigned)(p + 1)) : "memory");
    }
    __syncthreads();
  }

  // ---- output: exp(final v3) from layer-2 tiles ----
  if (w == 0) {
#pragma unroll
    for (int i = 0; i < 3; ++i) {
      if (lay[i] != 2) continue;
      const int h = hh[i] + lr;
      if (h < Hn) {
#pragma unroll
        for (int j = 0; j < 16; ++j) {
          const int row = (j & 3) + 8 * (j >> 2) + 4 * lg;
          out[(size_t)(b0 + row) * Hn + h] = expf(v[i][j]);
        }
      }
    }
  }
}

// ======================= PRIMARY: snn_pipe (ring-decoupled gates) ===========
__global__ void __launch_bounds__(256, 1)
snn_pipe(const float* __restrict__ x, const float* __restrict__ W1,
         unsigned char* __restrict__ ws, float* __restrict__ out)
{
  __shared__ float lds[12288];
  snn_body<1>(x, W1, ws, out, lds);
}

// ======================= FALLBACK: snn_bits (r16 verbatim, proven 10.3 ms) ==
__global__ void __launch_bounds__(256, 1)
snn_bits(const float* __restrict__ x, const float* __restrict__ W1,
         unsigned char* __restrict__ ws, float* __restrict__ out)
{
  __shared__ float lds[12288];
  snn_body<0>(x, W1, ws, out, lds);
}

// ======================= launcher =======================
extern "C" void kernel_launch(void* const* d_in, const int* in_sizes, int n_in,
                              void* d_out, int out_size, void* d_ws, size_t ws_size,
                              hipStream_t stream) {
  const float* x  = (const float*)d_in[0];
  const float* W1 = (const float*)d_in[1];
  const float* R1 = (const float*)d_in[2];
  const float* W2 = (const float*)d_in[3];
  const float* R2 = (const float*)d_in[4];
  const float* W3 = (const float*)d_in[5];
  const float* R3 = (const float*)d_in[6];
  float* out = (float*)d_out;
  unsigned char* ws = (unsigned char*)d_ws;
  (void)ws_size;   // layout identical to r10..r16 (12.08 MB, proven present)

  // bf16 weight prep + zero spike region / flag area (every launch/replay)
  hipLaunchKernelGGL(prep_w, dim3(20480), dim3(256), 0, stream,
                     R1, W2, R2, W3, R3, ws);
  hipMemsetAsync(ws + SB_OFF, 0, SB_BYTES + BAR_BYTES, stream);

  void* args[] = { (void*)&x, (void*)&W1, (void*)&ws, (void*)&out };

  if (hipLaunchCooperativeKernel((const void*)snn_pipe, dim3(NBLK), dim3(256),
                                 args, 0, stream) == hipSuccess)
    return;
  // fallback: r16 kernel (proven 10.3 ms)
  hipLaunchCooperativeKernel((const void*)snn_bits, dim3(NBLK), dim3(256),
                             args, 0, stream);
}

// Round 18
// 8154.252 us; speedup vs baseline: 1.8952x; 1.1403x over previous
//
#include <hip/hip_runtime.h>

// Problem constants
constexpr int Bsz = 256, Lf = 14, Tt = 500, Hn = 1000;
constexpr int HP = 1024, KP = 1024;     // padded h/k extents
constexpr int NG = 8, GBLK = 32;        // 8 batch-groups of 32 blocks
constexpr int NBLK = 256;

// d_ws layout (region sizes identical to r10..r17)
constexpr size_t W_MAT    = (size_t)HP * KP * 2;        // 2 MB bf16 per matrix
constexpr size_t W_SH     = (size_t)HP * KP;            // shorts per matrix
constexpr size_t SB_OFF   = 5 * W_MAT;                  // 10,485,760
constexpr size_t SB_BYTES = (size_t)2 * 3 * NG * GBLK * KP;  // 1,572,864
constexpr size_t BAR_OFF  = SB_OFF + SB_BYTES;
constexpr size_t BAR_BYTES = 16384;   // 8 groups x 32 flags x 64 B

// bitplane geometry: bp[slot:2][layer:3][group:8] -> 4096 B = 32 rows x 128 B

typedef __attribute__((ext_vector_type(8)))  short    short8;  // 8 bf16
typedef __attribute__((ext_vector_type(16))) float    f32x16;
typedef __attribute__((ext_vector_type(4)))  unsigned u32x4v;

// ======================= prep kernel (bf16 weights) =======================
__device__ __forceinline__ unsigned short f2bf(float f) {
  unsigned u = __builtin_bit_cast(unsigned, f);
  unsigned r = (u + 0x7FFFu + ((u >> 16) & 1u)) >> 16;   // RNE
  return (unsigned short)r;
}

__global__ void prep_w(const float* __restrict__ R1, const float* __restrict__ W2,
                       const float* __restrict__ R2, const float* __restrict__ W3,
                       const float* __restrict__ R3, unsigned char* __restrict__ ws) {
  int id  = blockIdx.x * 256 + threadIdx.x;      // 5 * 2^20 threads
  int mat = id >> 20;
  int rem = id & 0xFFFFF;
  int h   = rem >> 10;
  int k   = rem & 1023;
  const float* src = (mat == 0) ? R1 : (mat == 1) ? W2 : (mat == 2) ? R2
                    : (mat == 3) ? W3 : R3;
  float v = (h < Hn && k < Hn) ? src[(size_t)h * Hn + k] : 0.f;
  ((unsigned short*)ws)[(size_t)mat * W_SH + (size_t)h * KP + k] = f2bf(v);
}

// ======================= shared helpers =======================
__device__ __forceinline__ f32x16 MF(short8 a, const unsigned short* wp, f32x16 c) {
  short8 b = *(const short8*)wp;
  return __builtin_amdgcn_mfma_f32_32x32x16_bf16(a, b, c, 0, 0, 0);
}

// 8 spike BITS -> 8 bf16 (0.0/1.0)
__device__ __forceinline__ short8 expandBits(unsigned bt) {
  unsigned r0 = (bt & 1u)        * 0x3F80u + (bt & 2u)        * 0x1FC00000u;
  unsigned r1 = ((bt >> 2) & 1u) * 0x3F80u + ((bt >> 2) & 2u) * 0x1FC00000u;
  unsigned r2 = ((bt >> 4) & 1u) * 0x3F80u + ((bt >> 4) & 2u) * 0x1FC00000u;
  unsigned r3 = ((bt >> 6) & 1u) * 0x3F80u + ((bt >> 6) & 2u) * 0x1FC00000u;
  u32x4v u = {r0, r1, r2, r3};
  return __builtin_bit_cast(short8, u);
}

// byte (kc*2+lg) of a full 128B row held as q[8] (kc compile-time 0..63)
__device__ __forceinline__ unsigned bsel8(const u32x4v q[8], int kc, unsigned shl) {
  unsigned d = q[kc >> 3][(kc >> 1) & 3];
  return (d >> (((kc & 1) << 4) + shl)) & 0xFFu;
}

// full 128B bit-row load (8 x dwordx4), NO wait
__device__ __forceinline__ void ldplane(const unsigned char* p, u32x4v q[8]) {
  asm volatile(
    "global_load_dwordx4 %0, %8, off sc0 sc1\n\t"
    "global_load_dwordx4 %1, %8, off offset:16 sc0 sc1\n\t"
    "global_load_dwordx4 %2, %8, off offset:32 sc0 sc1\n\t"
    "global_load_dwordx4 %3, %8, off offset:48 sc0 sc1\n\t"
    "global_load_dwordx4 %4, %8, off offset:64 sc0 sc1\n\t"
    "global_load_dwordx4 %5, %8, off offset:80 sc0 sc1\n\t"
    "global_load_dwordx4 %6, %8, off offset:96 sc0 sc1\n\t"
    "global_load_dwordx4 %7, %8, off offset:112 sc0 sc1"
    : "=&v"(q[0]), "=&v"(q[1]), "=&v"(q[2]), "=&v"(q[3]),
      "=&v"(q[4]), "=&v"(q[5]), "=&v"(q[6]), "=&v"(q[7])
    : "v"(p) : "memory");
}

// 32B slice load (fallback kernel; r17 verbatim)
__device__ __forceinline__ void bits3(const unsigned char* p0,
    const unsigned char* p1, const unsigned char* p2,
    u32x4v& a0, u32x4v& b0, u32x4v& a1, u32x4v& b1, u32x4v& a2, u32x4v& b2) {
  asm volatile(
    "global_load_dwordx4 %0, %6, off sc0 sc1\n\t"
    "global_load_dwordx4 %1, %6, off offset:16 sc0 sc1\n\t"
    "global_load_dwordx4 %2, %7, off sc0 sc1\n\t"
    "global_load_dwordx4 %3, %7, off offset:16 sc0 sc1\n\t"
    "global_load_dwordx4 %4, %8, off sc0 sc1\n\t"
    "global_load_dwordx4 %5, %8, off offset:16 sc0 sc1\n\t"
    "s_waitcnt vmcnt(0)"
    : "=&v"(a0), "=&v"(b0), "=&v"(a1), "=&v"(b1), "=&v"(a2), "=&v"(b2)
    : "v"(p0), "v"(p1), "v"(p2) : "memory");
}
__device__ __forceinline__ unsigned bsel(const u32x4v& a, const u32x4v& b,
                                         int kc, unsigned shl) {
  unsigned q = (kc < 8) ? a[(unsigned)(kc >> 1)] : b[(unsigned)((kc - 8) >> 1)];
  return (q >> (((kc & 1) << 4) + shl)) & 0xFFu;
}

// block-level gate threshold offset (shared by both kernels)
__device__ __forceinline__ unsigned gate_off(int r, int lb) {
  bool rdP[3] = {false, false, false}, wrP[3] = {false, false, false};
#pragma unroll
  for (int i = 0; i < 3; ++i) {
    const int lay = (r * 3 + i) >> 5;
    if (lay == 0)      { rdP[0] = true; wrP[0] = true; }
    else if (lay == 1) { rdP[0] = true; rdP[1] = true; wrP[1] = true; }
    else               { rdP[1] = true; rdP[2] = true; wrP[2] = true; }
  }
  const bool isP[3] = { lb <= 10, lb >= 10 && lb <= 21, lb >= 21 };
  const bool isC[3] = { lb <= 21, lb >= 10, lb >= 21 };
  bool prod = false, cons = false;
#pragma unroll
  for (int pl = 0; pl < 3; ++pl) {
    prod |= rdP[pl] && isP[pl];
    cons |= wrP[pl] && isC[pl];
  }
  return prod ? 0u : (cons ? 1u : 0x40000000u);
}

// ======================= PRIMARY: snn_wave (tile-per-wave, no LDS) ==========
__global__ void __launch_bounds__(256, 1)
snn_wave(const float* __restrict__ x, const float* __restrict__ W1,
         unsigned char* __restrict__ ws, float* __restrict__ out)
{
  const int tid = threadIdx.x;
  const int l   = tid & 63;
  const int w   = tid >> 6;       // waves 0-2 own tiles; wave 3 polls the gate
  const int lr  = l & 31;         // A-row (b) / B-col (h)
  const int lg  = l >> 5;         // k lane-group
  const int blk = blockIdx.x;
  const int g   = blk >> 5;       // batch group
  const int r   = blk & 31;       // rank -> 3 row-tiles
  const int b0  = g * GBLK;
  const unsigned shl = (unsigned)lg * 8u;

  unsigned char* sb  = ws + SB_OFF;
  unsigned*      bar = (unsigned*)(ws + BAR_OFF);
  unsigned*      myflag = bar + ((size_t)g * GBLK + r) * 16;
  unsigned*      lanef  = bar + ((size_t)g * GBLK + (l & 31)) * 16;
  const unsigned short* wb = (const unsigned short*)ws;

  // this wave's tile (wave 3 mirrors tile 0 but does no work)
  const int ti  = (w < 3) ? w : 0;
  const int rt  = r * 3 + ti;
  const int lay = rt >> 5;
  const int hh  = (rt & 31) * 32;
  const size_t wl = (size_t)(hh + lr) * KP + lg * 8;
  const unsigned short *wA, *wB;
  int plA, plB;
  if (lay == 0)      { wA = wb + 0 * W_SH + wl; wB = wA;              plA = 0; plB = 0; }
  else if (lay == 1) { wA = wb + 1 * W_SH + wl; wB = wb + 2 * W_SH + wl; plA = 0; plB = 1; }
  else               { wA = wb + 3 * W_SH + wl; wB = wb + 4 * W_SH + wl; plA = 1; plB = 2; }

  const unsigned off = gate_off(r, l & 31);

  // hoisted W1 row for in-register F (lay-0 waves)
  float w1r[Lf];
#pragma unroll
  for (int t = 0; t < Lf; ++t)
    w1r[t] = ((hh + lr) < Hn) ? W1[(size_t)(hh + lr) * Lf + t] : 0.f;

  f32x16 v;
#pragma unroll
  for (int j = 0; j < 16; ++j) v[j] = 0.f;

#pragma unroll 1
  for (int p = 0; p < Tt + 2; ++p) {
    const int srd = (p + 1) & 1;
    const int swr = p & 1;

    // ---- in-register F for lay-0 tile waves (x-only; above the gate) ----
    float Freg[16];
    if (w < 3 && lay == 0) {
#pragma unroll
      for (int j = 0; j < 16; ++j) {
        float F = 0.f;
        if (p < Tt) {
          const int row = (j & 3) + 8 * (j >> 2) + 4 * lg;   // batch
          const float* xr = x + (size_t)(b0 + row) * (Lf * Tt) + p;
#pragma unroll
          for (int t = 0; t < Lf; ++t)
            F = fmaf(xr[(size_t)t * Tt], w1r[t], F);
        }
        Freg[j] = F;
      }
    }

    // ---- gate: wave 3 polls all 32 group flags (thresholded) ----
    if (w == 3 && l < 32) {
      for (;;) {
        unsigned fv;
        asm volatile("global_load_dword %0, %1, off sc0 sc1\n\ts_waitcnt vmcnt(0)"
                     : "=v"(fv) : "v"(lanef) : "memory");
        if (__all(fv + off >= (unsigned)p)) break;
        __builtin_amdgcn_s_sleep(1);
      }
    }
    __syncthreads();

    if (w < 3) {
      // ---- full-K bit loads for this tile's plane(s), one round trip ----
      const size_t rowoff = (size_t)lr * 128;
      u32x4v qA[8], qB[8];
      ldplane(sb + (((size_t)srd * 3 + plA) * NG + g) * 4096 + rowoff, qA);
      if (lay != 0)
        ldplane(sb + (((size_t)srd * 3 + plB) * NG + g) * 4096 + rowoff, qB);
      asm volatile("s_waitcnt vmcnt(0)" ::: "memory");
      __builtin_amdgcn_sched_barrier(0);

      // ---- MFMA: full K (64 chunks), 1-2 matrices ----
      f32x16 acc;
#pragma unroll
      for (int j = 0; j < 16; ++j) acc[j] = 0.f;
      if (lay == 0) {
#pragma unroll
        for (int kc = 0; kc < 64; ++kc)
          acc = MF(expandBits(bsel8(qA, kc, shl)), wA + kc * 16, acc);
      } else {
#pragma unroll
        for (int kc = 0; kc < 64; ++kc) {
          acc = MF(expandBits(bsel8(qA, kc, shl)), wA + kc * 16, acc);
          acc = MF(expandBits(bsel8(qB, kc, shl)), wB + kc * 16, acc);
        }
      }

      // ---- per-wave LIF + ballot + bit stores ----
      unsigned char* ob = sb + (((size_t)swr * 3 + lay) * NG + g) * 4096 + (hh >> 3);
#pragma unroll
      for (int j = 0; j < 16; ++j) {
        const float hs = acc[j] + ((lay == 0) ? Freg[j] : 0.f);
        const float vn = 0.5f * (v[j] + hs);
        const unsigned c = (vn >= 1.0f) ? 1u : 0u;
        v[j] = c ? 0.f : vn;
        unsigned long long m = __ballot(c != 0u);
        if (l == 0) {
          const int r0 = (j & 3) + 8 * (j >> 2);
          asm volatile("global_store_dword %0, %1, off sc0 sc1"
                       :: "v"(ob + (size_t)r0 * 128), "v"((unsigned)m) : "memory");
          asm volatile("global_store_dword %0, %1, off sc0 sc1"
                       :: "v"(ob + (size_t)(r0 + 4) * 128),
                          "v"((unsigned)(m >> 32)) : "memory");
        }
      }
      asm volatile("s_waitcnt vmcnt(0)" ::: "memory");   // drain own stores
    }

    // ---- arrive: all waves drained -> single flag store (no RMW) ----
    __syncthreads();
    if (tid == 0) {
      asm volatile("global_store_dword %0, %1, off sc0 sc1"
                   :: "v"(myflag), "v"((unsigned)(p + 1)) : "memory");
    }
  }

  // ---- output: exp(final v3) from layer-2 tile waves ----
  if (w < 3 && lay == 2 && (hh + lr) < Hn) {
#pragma unroll
    for (int j = 0; j < 16; ++j) {
      const int row = (j & 3) + 8 * (j >> 2) + 4 * lg;
      out[(size_t)(b0 + row) * Hn + hh + lr] = expf(v[j]);
    }
  }
}

// ======================= FALLBACK: snn_pipe (r17 verbatim, proven 9.3 ms) ===
__global__ void __launch_bounds__(256, 1)
snn_pipe(const float* __restrict__ x, const float* __restrict__ W1,
         unsigned char* __restrict__ ws, float* __restrict__ out)
{
  __shared__ float lds[12288];

  const int tid = threadIdx.x;
  const int l   = tid & 63;
  const int w   = tid >> 6;
  const int lr  = l & 31;
  const int lg  = l >> 5;
  const int blk = blockIdx.x;
  const int g   = blk >> 5;
  const int r   = blk & 31;
  const int b0  = g * GBLK;
  const unsigned shl = (unsigned)lg * 8u;

  unsigned char* sb  = ws + SB_OFF;
  unsigned*      bar = (unsigned*)(ws + BAR_OFF);
  unsigned*      myflag = bar + ((size_t)g * GBLK + r) * 16;
  unsigned*      lanef  = bar + ((size_t)g * GBLK + (l & 31)) * 16;
  const unsigned short* wb = (const unsigned short*)ws;

  int lay[3], hh[3];
  const unsigned short *wA[3], *wB[3];
#pragma unroll
  for (int i = 0; i < 3; ++i) {
    const int rt = r * 3 + i;
    lay[i] = rt >> 5;
    hh[i]  = (rt & 31) * 32;
    const size_t wl = (size_t)(hh[i] + lr) * KP + w * 256 + lg * 8;
    if (lay[i] == 0)      { wA[i] = wb + 0 * W_SH + wl; wB[i] = wb + 0 * W_SH + wl; }
    else if (lay[i] == 1) { wA[i] = wb + 1 * W_SH + wl; wB[i] = wb + 2 * W_SH + wl; }
    else                  { wA[i] = wb + 3 * W_SH + wl; wB[i] = wb + 4 * W_SH + wl; }
  }

  const unsigned off = gate_off(r, l & 31);

  f32x16 v[3];
#pragma unroll
  for (int i = 0; i < 3; ++i)
#pragma unroll
    for (int j = 0; j < 16; ++j) v[i][j] = 0.f;

#pragma unroll 1
  for (int p = 0; p < Tt + 2; ++p) {
    const int srd = (p + 1) & 1;
    const int swr = p & 1;

#pragma unroll
    for (int i = 0; i < 3; ++i) {
      if (lay[i] != 0) continue;
      const int fh = tid & 31;
      const int fb = tid >> 5;
      float F0 = 0.f, F1 = 0.f, F2 = 0.f, F3 = 0.f;
      if (p < Tt) {
        const int hrow = hh[i] + fh;
        const float* xq0 = x + (size_t)(b0 + fb)      * (Lf * Tt) + p;
        const float* xq1 = x + (size_t)(b0 + fb + 8)  * (Lf * Tt) + p;
        const float* xq2 = x + (size_t)(b0 + fb + 16) * (Lf * Tt) + p;
        const float* xq3 = x + (size_t)(b0 + fb + 24) * (Lf * Tt) + p;
        const float* w1p = W1 + (size_t)hrow * Lf;
#pragma unroll
        for (int t = 0; t < Lf; ++t) {
          const float wv = (hrow < Hn) ? w1p[t] : 0.f;
          F0 = fmaf(xq0[(size_t)t * Tt], wv, F0);
          F1 = fmaf(xq1[(size_t)t * Tt], wv, F1);
          F2 = fmaf(xq2[(size_t)t * Tt], wv, F2);
          F3 = fmaf(xq3[(size_t)t * Tt], wv, F3);
        }
      }
      float* Fp = &lds[9216 + i * 1024 + fb * 32 + fh];
      Fp[0]       = F0;
      Fp[8 * 32]  = F1;
      Fp[16 * 32] = F2;
      Fp[24 * 32] = F3;
    }

    if (tid < 64) {
      for (;;) {
        unsigned fv;
        asm volatile("global_load_dword %0, %1, off sc0 sc1\n\ts_waitcnt vmcnt(0)"
                     : "=v"(fv) : "v"(lanef) : "memory");
        if (__all(fv + off >= (unsigned)p)) break;
        __builtin_amdgcn_s_sleep(1);
      }
    }
    __syncthreads();

    const size_t lslice = (size_t)lr * 128 + (size_t)w * 32;
    const unsigned char* p0 = sb + (((size_t)srd * 3 + 0) * NG + g) * 4096 + lslice;
    const unsigned char* p1 = sb + (((size_t)srd * 3 + 1) * NG + g) * 4096 + lslice;
    const unsigned char* p2 = sb + (((size_t)srd * 3 + 2) * NG + g) * 4096 + lslice;
    u32x4v qa0, qb0, qa1, qb1, qa2, qb2;
    bits3(p0, p1, p2, qa0, qb0, qa1, qb1, qa2, qb2);
    __builtin_amdgcn_sched_barrier(0);

    f32x16 acc[3];
#pragma unroll
    for (int i = 0; i < 3; ++i) {
#pragma unroll
      for (int j = 0; j < 16; ++j) acc[i][j] = 0.f;
      if (lay[i] == 0) {
#pragma unroll
        for (int kc = 0; kc < 16; ++kc)
          acc[i] = MF(expandBits(bsel(qa0, qb0, kc, shl)), wA[i] + kc * 16, acc[i]);
      } else if (lay[i] == 1) {
#pragma unroll
        for (int kc = 0; kc < 16; ++kc) {
          acc[i] = MF(expandBits(bsel(qa0, qb0, kc, shl)), wA[i] + kc * 16, acc[i]);
          acc[i] = MF(expandBits(bsel(qa1, qb1, kc, shl)), wB[i] + kc * 16, acc[i]);
        }
      } else {
#pragma unroll
        for (int kc = 0; kc < 16; ++kc) {
          acc[i] = MF(expandBits(bsel(qa1, qb1, kc, shl)), wA[i] + kc * 16, acc[i]);
          acc[i] = MF(expandBits(bsel(qa2, qb2, kc, shl)), wB[i] + kc * 16, acc[i]);
        }
      }
    }

    if (w != 0) {
      float* dp = &lds[(w - 1) * 3 * 1024 + l];
#pragma unroll
      for (int i = 0; i < 3; ++i)
#pragma unroll
        for (int j = 0; j < 16; ++j) dp[i * 1024 + j * 64] = acc[i][j];
    }
    __syncthreads();

    if (w == 0) {
#pragma unroll
      for (int i = 0; i < 3; ++i) {
        unsigned char* ob = sb + (((size_t)swr * 3 + lay[i]) * NG + g) * 4096
                            + (hh[i] >> 3);
#pragma unroll
        for (int j = 0; j < 16; ++j) {
          const int row = (j & 3) + 8 * (j >> 2) + 4 * lg;
          float a = acc[i][j];
#pragma unroll
          for (int ww = 0; ww < 3; ++ww)
            a += lds[(ww * 3 + i) * 1024 + j * 64 + l];
          const float F = (lay[i] == 0) ? lds[9216 + i * 1024 + row * 32 + lr] : 0.f;
          const float vn = 0.5f * (v[i][j] + a + F);
          const unsigned c = (vn >= 1.0f) ? 1u : 0u;
          v[i][j] = c ? 0.f : vn;
          unsigned long long m = __ballot(c != 0u);
          if (l == 0) {
            const int r0 = (j & 3) + 8 * (j >> 2);
            asm volatile("global_store_dword %0, %1, off sc0 sc1"
                         :: "v"(ob + (size_t)r0 * 128), "v"((unsigned)m) : "memory");
            asm volatile("global_store_dword %0, %1, off sc0 sc1"
                         :: "v"(ob + (size_t)(r0 + 4) * 128),
                            "v"((unsigned)(m >> 32)) : "memory");
          }
        }
      }
    }

    asm volatile("s_waitcnt vmcnt(0)" ::: "memory");
    __syncthreads();
    if (tid == 0) {
      asm volatile("global_store_dword %0, %1, off sc0 sc1"
                   :: "v"(myflag), "v"((unsigned)(p + 1)) : "memory");
    }
    __syncthreads();
  }

  if (w == 0) {
#pragma unroll
    for (int i = 0; i < 3; ++i) {
      if (lay[i] != 2) continue;
      const int h = hh[i] + lr;
      if (h < Hn) {
#pragma unroll
        for (int j = 0; j < 16; ++j) {
          const int row = (j & 3) + 8 * (j >> 2) + 4 * lg;
          out[(size_t)(b0 + row) * Hn + h] = expf(v[i][j]);
        }
      }
    }
  }
}

// ======================= launcher =======================
extern "C" void kernel_launch(void* const* d_in, const int* in_sizes, int n_in,
                              void* d_out, int out_size, void* d_ws, size_t ws_size,
                              hipStream_t stream) {
  const float* x  = (const float*)d_in[0];
  const float* W1 = (const float*)d_in[1];
  const float* R1 = (const float*)d_in[2];
  const float* W2 = (const float*)d_in[3];
  const float* R2 = (const float*)d_in[4];
  const float* W3 = (const float*)d_in[5];
  const float* R3 = (const float*)d_in[6];
  float* out = (float*)d_out;
  unsigned char* ws = (unsigned char*)d_ws;
  (void)ws_size;   // layout identical to r10..r17 (12.08 MB, proven present)

  // bf16 weight prep + zero spike region / flag area (every launch/replay)
  hipLaunchKernelGGL(prep_w, dim3(20480), dim3(256), 0, stream,
                     R1, W2, R2, W3, R3, ws);
  hipMemsetAsync(ws + SB_OFF, 0, SB_BYTES + BAR_BYTES, stream);

  void* args[] = { (void*)&x, (void*)&W1, (void*)&ws, (void*)&out };

  if (hipLaunchCooperativeKernel((const void*)snn_wave, dim3(NBLK), dim3(256),
                                 args, 0, stream) == hipSuccess)
    return;
  // fallback: r17 kernel (proven 9.3 ms)
  hipLaunchCooperativeKernel((const void*)snn_pipe, dim3(NBLK), dim3(256),
                             args, 0, stream);
}

// Round 19
// 8021.200 us; speedup vs baseline: 1.9266x; 1.0166x over previous
//
#include <hip/hip_runtime.h>

// Problem constants
constexpr int Bsz = 256, Lf = 14, Tt = 500, Hn = 1000;
constexpr int HP = 1024, KP = 1024;     // padded h/k extents
constexpr int NG = 8, GBLK = 32;        // 8 batch-groups of 32 blocks
constexpr int NBLK = 256;

// d_ws layout (region sizes identical to r10..r18)
constexpr size_t W_MAT    = (size_t)HP * KP * 2;        // 2 MB bf16 per matrix
constexpr size_t W_SH     = (size_t)HP * KP;            // shorts per matrix
constexpr size_t SB_OFF   = 5 * W_MAT;                  // 10,485,760
constexpr size_t SB_BYTES = (size_t)2 * 3 * NG * GBLK * KP;  // 1,572,864 (covers 3-slot planes)
constexpr size_t BAR_OFF  = SB_OFF + SB_BYTES;
constexpr size_t BAR_BYTES = 16384;   // 8 groups x 32 flags x 64 B

// bitplane geometry: bp[slot][layer:3][group:8] -> 4096 B = 32 rows x 128 B
// PRIMARY uses slot:3 (race-free ring lag); FALLBACK uses slot:2 (r18).

typedef __attribute__((ext_vector_type(8)))  short    short8;  // 8 bf16
typedef __attribute__((ext_vector_type(16))) float    f32x16;
typedef __attribute__((ext_vector_type(4)))  unsigned u32x4v;

// ======================= prep kernel (bf16 weights) =======================
__device__ __forceinline__ unsigned short f2bf(float f) {
  unsigned u = __builtin_bit_cast(unsigned, f);
  unsigned r = (u + 0x7FFFu + ((u >> 16) & 1u)) >> 16;   // RNE
  return (unsigned short)r;
}

__global__ void prep_w(const float* __restrict__ R1, const float* __restrict__ W2,
                       const float* __restrict__ R2, const float* __restrict__ W3,
                       const float* __restrict__ R3, unsigned char* __restrict__ ws) {
  int id  = blockIdx.x * 256 + threadIdx.x;      // 5 * 2^20 threads
  int mat = id >> 20;
  int rem = id & 0xFFFFF;
  int h   = rem >> 10;
  int k   = rem & 1023;
  const float* src = (mat == 0) ? R1 : (mat == 1) ? W2 : (mat == 2) ? R2
                    : (mat == 3) ? W3 : R3;
  float v = (h < Hn && k < Hn) ? src[(size_t)h * Hn + k] : 0.f;
  ((unsigned short*)ws)[(size_t)mat * W_SH + (size_t)h * KP + k] = f2bf(v);
}

// ======================= shared helpers =======================
__device__ __forceinline__ f32x16 MF(short8 a, const unsigned short* wp, f32x16 c) {
  short8 b = *(const short8*)wp;
  return __builtin_amdgcn_mfma_f32_32x32x16_bf16(a, b, c, 0, 0, 0);
}

// 8 spike BITS -> 8 bf16 (0.0/1.0)
__device__ __forceinline__ short8 expandBits(unsigned bt) {
  unsigned r0 = (bt & 1u)        * 0x3F80u + (bt & 2u)        * 0x1FC00000u;
  unsigned r1 = ((bt >> 2) & 1u) * 0x3F80u + ((bt >> 2) & 2u) * 0x1FC00000u;
  unsigned r2 = ((bt >> 4) & 1u) * 0x3F80u + ((bt >> 4) & 2u) * 0x1FC00000u;
  unsigned r3 = ((bt >> 6) & 1u) * 0x3F80u + ((bt >> 6) & 2u) * 0x1FC00000u;
  u32x4v u = {r0, r1, r2, r3};
  return __builtin_bit_cast(short8, u);
}

// byte (kc*2+lg) of a full 128B row held as q[8] (kc compile-time 0..63)
__device__ __forceinline__ unsigned bsel8(const u32x4v q[8], int kc, unsigned shl) {
  unsigned d = q[kc >> 3][(kc >> 1) & 3];
  return (d >> (((kc & 1) << 4) + shl)) & 0xFFu;
}

// full 128B bit-row load (8 x dwordx4), NO wait
__device__ __forceinline__ void ldplane(const unsigned char* p, u32x4v q[8]) {
  asm volatile(
    "global_load_dwordx4 %0, %8, off sc0 sc1\n\t"
    "global_load_dwordx4 %1, %8, off offset:16 sc0 sc1\n\t"
    "global_load_dwordx4 %2, %8, off offset:32 sc0 sc1\n\t"
    "global_load_dwordx4 %3, %8, off offset:48 sc0 sc1\n\t"
    "global_load_dwordx4 %4, %8, off offset:64 sc0 sc1\n\t"
    "global_load_dwordx4 %5, %8, off offset:80 sc0 sc1\n\t"
    "global_load_dwordx4 %6, %8, off offset:96 sc0 sc1\n\t"
    "global_load_dwordx4 %7, %8, off offset:112 sc0 sc1"
    : "=&v"(q[0]), "=&v"(q[1]), "=&v"(q[2]), "=&v"(q[3]),
      "=&v"(q[4]), "=&v"(q[5]), "=&v"(q[6]), "=&v"(q[7])
    : "v"(p) : "memory");
}

// block-level gate threshold offset (shared by both kernels)
__device__ __forceinline__ unsigned gate_off(int r, int lb) {
  bool rdP[3] = {false, false, false}, wrP[3] = {false, false, false};
#pragma unroll
  for (int i = 0; i < 3; ++i) {
    const int lay = (r * 3 + i) >> 5;
    if (lay == 0)      { rdP[0] = true; wrP[0] = true; }
    else if (lay == 1) { rdP[0] = true; rdP[1] = true; wrP[1] = true; }
    else               { rdP[1] = true; rdP[2] = true; wrP[2] = true; }
  }
  const bool isP[3] = { lb <= 10, lb >= 10 && lb <= 21, lb >= 21 };
  const bool isC[3] = { lb <= 21, lb >= 10, lb >= 21 };
  bool prod = false, cons = false;
#pragma unroll
  for (int pl = 0; pl < 3; ++pl) {
    prod |= rdP[pl] && isP[pl];
    cons |= wrP[pl] && isC[pl];
  }
  return prod ? 0u : (cons ? 1u : 0x40000000u);
}

// ======== PRIMARY: snn_ring (3-slot race-free + overlapped gate) ============
__global__ void __launch_bounds__(256, 1)
snn_ring(const float* __restrict__ x, const float* __restrict__ W1,
         unsigned char* __restrict__ ws, float* __restrict__ out)
{
  __shared__ unsigned dcnt;   // compute-wave arrival counter (monotone)

  const int tid = threadIdx.x;
  const int l   = tid & 63;
  const int w   = tid >> 6;       // waves 0-2 own tiles; wave 3 polls the gate
  const int lr  = l & 31;
  const int lg  = l >> 5;
  const int blk = blockIdx.x;
  const int g   = blk >> 5;
  const int r   = blk & 31;
  const int b0  = g * GBLK;
  const unsigned shl = (unsigned)lg * 8u;

  unsigned char* sb  = ws + SB_OFF;
  unsigned*      bar = (unsigned*)(ws + BAR_OFF);
  unsigned*      myflag = bar + ((size_t)g * GBLK + r) * 16;
  unsigned*      lanef  = bar + ((size_t)g * GBLK + (l & 31)) * 16;
  const unsigned short* wb = (const unsigned short*)ws;

  // this wave's tile (wave 3 mirrors tile 0 but does no compute)
  const int ti  = (w < 3) ? w : 0;
  const int rt  = r * 3 + ti;
  const int lay = rt >> 5;
  const int hh  = (rt & 31) * 32;
  const size_t wl = (size_t)(hh + lr) * KP + lg * 8;
  const unsigned short *wA, *wB;
  int plA, plB;
  if (lay == 0)      { wA = wb + 0 * W_SH + wl; wB = wA;               plA = 0; plB = 0; }
  else if (lay == 1) { wA = wb + 1 * W_SH + wl; wB = wb + 2 * W_SH + wl; plA = 0; plB = 1; }
  else               { wA = wb + 3 * W_SH + wl; wB = wb + 4 * W_SH + wl; plA = 1; plB = 2; }

  const unsigned off = gate_off(r, l & 31);

  float w1r[Lf];
#pragma unroll
  for (int t = 0; t < Lf; ++t)
    w1r[t] = ((hh + lr) < Hn) ? W1[(size_t)(hh + lr) * Lf + t] : 0.f;

  if (tid == 0) dcnt = 0;
  __syncthreads();

  f32x16 v;
#pragma unroll
  for (int j = 0; j < 16; ++j) v[j] = 0.f;

  int sw = 0, sr = 2;   // 3-slot rotation: write p%3, read (p+2)%3

#pragma unroll 1
  for (int p = 0; p < Tt + 2; ++p) {
    // invariant on entry: gate(p) satisfied (verified by wave 3 last iteration;
    // trivially true at p=0 since all flags are 0 and off>=0)
    if (w < 3) {
      // ---- in-register F for lay-0 tile waves ----
      float Freg[16];
      if (lay == 0) {
#pragma unroll
        for (int j = 0; j < 16; ++j) {
          float F = 0.f;
          if (p < Tt) {
            const int row = (j & 3) + 8 * (j >> 2) + 4 * lg;
            const float* xr = x + (size_t)(b0 + row) * (Lf * Tt) + p;
#pragma unroll
            for (int t = 0; t < Lf; ++t)
              F = fmaf(xr[(size_t)t * Tt], w1r[t], F);
          }
          Freg[j] = F;
        }
      }

      // ---- full-K bit loads (read slot sr), one round trip ----
      const size_t rowoff = (size_t)lr * 128;
      u32x4v qA[8], qB[8];
      ldplane(sb + (((size_t)sr * 3 + plA) * NG + g) * 4096 + rowoff, qA);
      if (lay != 0)
        ldplane(sb + (((size_t)sr * 3 + plB) * NG + g) * 4096 + rowoff, qB);
      asm volatile("s_waitcnt vmcnt(0)" ::: "memory");
      __builtin_amdgcn_sched_barrier(0);

      // ---- MFMA: full K (64 chunks), 1-2 matrices ----
      f32x16 acc;
#pragma unroll
      for (int j = 0; j < 16; ++j) acc[j] = 0.f;
      if (lay == 0) {
#pragma unroll
        for (int kc = 0; kc < 64; ++kc)
          acc = MF(expandBits(bsel8(qA, kc, shl)), wA + kc * 16, acc);
      } else {
#pragma unroll
        for (int kc = 0; kc < 64; ++kc) {
          acc = MF(expandBits(bsel8(qA, kc, shl)), wA + kc * 16, acc);
          acc = MF(expandBits(bsel8(qB, kc, shl)), wB + kc * 16, acc);
        }
      }

      // ---- per-wave LIF + ballot + bit stores (write slot sw) ----
      unsigned char* ob = sb + (((size_t)sw * 3 + lay) * NG + g) * 4096 + (hh >> 3);
#pragma unroll
      for (int j = 0; j < 16; ++j) {
        const float hs = acc[j] + ((lay == 0) ? Freg[j] : 0.f);
        const float vn = 0.5f * (v[j] + hs);
        const unsigned c = (vn >= 1.0f) ? 1u : 0u;
        v[j] = c ? 0.f : vn;
        unsigned long long m = __ballot(c != 0u);
        if (l == 0) {
          const int r0 = (j & 3) + 8 * (j >> 2);
          asm volatile("global_store_dword %0, %1, off sc0 sc1"
                       :: "v"(ob + (size_t)r0 * 128), "v"((unsigned)m) : "memory");
          asm volatile("global_store_dword %0, %1, off sc0 sc1"
                       :: "v"(ob + (size_t)(r0 + 4) * 128),
                          "v"((unsigned)(m >> 32)) : "memory");
        }
      }
      asm volatile("s_waitcnt vmcnt(0)" ::: "memory");   // drain own stores

      // ---- LDS arrival; wave0-lane0 publishes the block flag (no wave-3 dep) ----
      if (l == 0)
        __hip_atomic_fetch_add(&dcnt, 1u, __ATOMIC_RELAXED,
                               __HIP_MEMORY_SCOPE_WORKGROUP);
      if (w == 0 && l == 0) {
        while (__hip_atomic_load(&dcnt, __ATOMIC_RELAXED,
                                 __HIP_MEMORY_SCOPE_WORKGROUP) < 3u * (unsigned)(p + 1)) {}
        asm volatile("global_store_dword %0, %1, off sc0 sc1"
                     :: "v"(myflag), "v"((unsigned)(p + 1)) : "memory");
      }
    } else if (l < 32 && p < Tt + 1) {
      // ---- wave 3: poll gate(p+1) DURING compute (overlapped) ----
      for (;;) {
        unsigned fv;
        asm volatile("global_load_dword %0, %1, off sc0 sc1\n\ts_waitcnt vmcnt(0)"
                     : "=v"(fv) : "v"(lanef) : "memory");
        if (__all(fv + off >= (unsigned)(p + 1))) break;
        __builtin_amdgcn_s_sleep(1);
      }
    }
    __syncthreads();   // single barrier: gate(p+1) verified, stores flagged

    sw = (sw == 2) ? 0 : sw + 1;
    sr = (sr == 2) ? 0 : sr + 1;
  }

  // ---- output: exp(final v3) from layer-2 tile waves ----
  if (w < 3 && lay == 2 && (hh + lr) < Hn) {
#pragma unroll
    for (int j = 0; j < 16; ++j) {
      const int row = (j & 3) + 8 * (j >> 2) + 4 * lg;
      out[(size_t)(b0 + row) * Hn + hh + lr] = expf(v[j]);
    }
  }
}

// ======================= FALLBACK: snn_wave (r18 verbatim, proven 8.15 ms) ==
__global__ void __launch_bounds__(256, 1)
snn_wave(const float* __restrict__ x, const float* __restrict__ W1,
         unsigned char* __restrict__ ws, float* __restrict__ out)
{
  const int tid = threadIdx.x;
  const int l   = tid & 63;
  const int w   = tid >> 6;
  const int lr  = l & 31;
  const int lg  = l >> 5;
  const int blk = blockIdx.x;
  const int g   = blk >> 5;
  const int r   = blk & 31;
  const int b0  = g * GBLK;
  const unsigned shl = (unsigned)lg * 8u;

  unsigned char* sb  = ws + SB_OFF;
  unsigned*      bar = (unsigned*)(ws + BAR_OFF);
  unsigned*      myflag = bar + ((size_t)g * GBLK + r) * 16;
  unsigned*      lanef  = bar + ((size_t)g * GBLK + (l & 31)) * 16;
  const unsigned short* wb = (const unsigned short*)ws;

  const int ti  = (w < 3) ? w : 0;
  const int rt  = r * 3 + ti;
  const int lay = rt >> 5;
  const int hh  = (rt & 31) * 32;
  const size_t wl = (size_t)(hh + lr) * KP + lg * 8;
  const unsigned short *wA, *wB;
  int plA, plB;
  if (lay == 0)      { wA = wb + 0 * W_SH + wl; wB = wA;               plA = 0; plB = 0; }
  else if (lay == 1) { wA = wb + 1 * W_SH + wl; wB = wb + 2 * W_SH + wl; plA = 0; plB = 1; }
  else               { wA = wb + 3 * W_SH + wl; wB = wb + 4 * W_SH + wl; plA = 1; plB = 2; }

  const unsigned off = gate_off(r, l & 31);

  float w1r[Lf];
#pragma unroll
  for (int t = 0; t < Lf; ++t)
    w1r[t] = ((hh + lr) < Hn) ? W1[(size_t)(hh + lr) * Lf + t] : 0.f;

  f32x16 v;
#pragma unroll
  for (int j = 0; j < 16; ++j) v[j] = 0.f;

#pragma unroll 1
  for (int p = 0; p < Tt + 2; ++p) {
    const int srd = (p + 1) & 1;
    const int swr = p & 1;

    float Freg[16];
    if (w < 3 && lay == 0) {
#pragma unroll
      for (int j = 0; j < 16; ++j) {
        float F = 0.f;
        if (p < Tt) {
          const int row = (j & 3) + 8 * (j >> 2) + 4 * lg;
          const float* xr = x + (size_t)(b0 + row) * (Lf * Tt) + p;
#pragma unroll
          for (int t = 0; t < Lf; ++t)
            F = fmaf(xr[(size_t)t * Tt], w1r[t], F);
        }
        Freg[j] = F;
      }
    }

    if (w == 3 && l < 32) {
      for (;;) {
        unsigned fv;
        asm volatile("global_load_dword %0, %1, off sc0 sc1\n\ts_waitcnt vmcnt(0)"
                     : "=v"(fv) : "v"(lanef) : "memory");
        if (__all(fv + off >= (unsigned)p)) break;
        __builtin_amdgcn_s_sleep(1);
      }
    }
    __syncthreads();

    if (w < 3) {
      const size_t rowoff = (size_t)lr * 128;
      u32x4v qA[8], qB[8];
      ldplane(sb + (((size_t)srd * 3 + plA) * NG + g) * 4096 + rowoff, qA);
      if (lay != 0)
        ldplane(sb + (((size_t)srd * 3 + plB) * NG + g) * 4096 + rowoff, qB);
      asm volatile("s_waitcnt vmcnt(0)" ::: "memory");
      __builtin_amdgcn_sched_barrier(0);

      f32x16 acc;
#pragma unroll
      for (int j = 0; j < 16; ++j) acc[j] = 0.f;
      if (lay == 0) {
#pragma unroll
        for (int kc = 0; kc < 64; ++kc)
          acc = MF(expandBits(bsel8(qA, kc, shl)), wA + kc * 16, acc);
      } else {
#pragma unroll
        for (int kc = 0; kc < 64; ++kc) {
          acc = MF(expandBits(bsel8(qA, kc, shl)), wA + kc * 16, acc);
          acc = MF(expandBits(bsel8(qB, kc, shl)), wB + kc * 16, acc);
        }
      }

      unsigned char* ob = sb + (((size_t)swr * 3 + lay) * NG + g) * 4096 + (hh >> 3);
#pragma unroll
      for (int j = 0; j < 16; ++j) {
        const float hs = acc[j] + ((lay == 0) ? Freg[j] : 0.f);
        const float vn = 0.5f * (v[j] + hs);
        const unsigned c = (vn >= 1.0f) ? 1u : 0u;
        v[j] = c ? 0.f : vn;
        unsigned long long m = __ballot(c != 0u);
        if (l == 0) {
          const int r0 = (j & 3) + 8 * (j >> 2);
          asm volatile("global_store_dword %0, %1, off sc0 sc1"
                       :: "v"(ob + (size_t)r0 * 128), "v"((unsigned)m) : "memory");
          asm volatile("global_store_dword %0, %1, off sc0 sc1"
                       :: "v"(ob + (size_t)(r0 + 4) * 128),
                          "v"((unsigned)(m >> 32)) : "memory");
        }
      }
      asm volatile("s_waitcnt vmcnt(0)" ::: "memory");
    }

    __syncthreads();
    if (tid == 0) {
      asm volatile("global_store_dword %0, %1, off sc0 sc1"
                   :: "v"(myflag), "v"((unsigned)(p + 1)) : "memory");
    }
  }

  if (w < 3 && lay == 2 && (hh + lr) < Hn) {
#pragma unroll
    for (int j = 0; j < 16; ++j) {
      const int row = (j & 3) + 8 * (j >> 2) + 4 * lg;
      out[(size_t)(b0 + row) * Hn + hh + lr] = expf(v[j]);
    }
  }
}

// ======================= launcher =======================
extern "C" void kernel_launch(void* const* d_in, const int* in_sizes, int n_in,
                              void* d_out, int out_size, void* d_ws, size_t ws_size,
                              hipStream_t stream) {
  const float* x  = (const float*)d_in[0];
  const float* W1 = (const float*)d_in[1];
  const float* R1 = (const float*)d_in[2];
  const float* W2 = (const float*)d_in[3];
  const float* R2 = (const float*)d_in[4];
  const float* W3 = (const float*)d_in[5];
  const float* R3 = (const float*)d_in[6];
  float* out = (float*)d_out;
  unsigned char* ws = (unsigned char*)d_ws;
  (void)ws_size;   // layout identical to r10..r18 (12.08 MB, proven present)

  // bf16 weight prep + zero spike region / flag area (every launch/replay)
  hipLaunchKernelGGL(prep_w, dim3(20480), dim3(256), 0, stream,
                     R1, W2, R2, W3, R3, ws);
  hipMemsetAsync(ws + SB_OFF, 0, SB_BYTES + BAR_BYTES, stream);

  void* args[] = { (void*)&x, (void*)&W1, (void*)&ws, (void*)&out };

  if (hipLaunchCooperativeKernel((const void*)snn_ring, dim3(NBLK), dim3(256),
                                 args, 0, stream) == hipSuccess)
    return;
  // fallback: r18 kernel (proven 8.15 ms)
  hipLaunchCooperativeKernel((const void*)snn_wave, dim3(NBLK), dim3(256),
                             args, 0, stream);
}